// Round 2
// baseline (275.070 us; speedup 1.0000x reference)
//
#include <hip/hip_runtime.h>
#include <hip/hip_bf16.h>

#define NN 768
#define LL 8
#define HH 64
#define IT 16     // attn i-tile
#define ABP 776   // bf16 alpha row stride (shorts); 1552 B, 16B-aligned
#define XST 80    // qkv LDS X-tile row stride in shorts (160 B, 16B-aligned)
#define WST 72    // staged-W LDS row stride in shorts (144 B = 9*16, 16B-aligned)
#define GRID 384

typedef __attribute__((ext_vector_type(8))) short bf16x8;
typedef __attribute__((ext_vector_type(4))) float f32x4;

__device__ __forceinline__ short f2bf(float x) {
    union { __hip_bfloat16 h; short s; } u;
    u.h = __float2bfloat16(x);
    return u.s;
}

__device__ __forceinline__ bf16x8 pack8(float4 lo, float4 hi) {
    bf16x8 r;
    r[0] = f2bf(lo.x); r[1] = f2bf(lo.y); r[2] = f2bf(lo.z); r[3] = f2bf(lo.w);
    r[4] = f2bf(hi.x); r[5] = f2bf(hi.y); r[6] = f2bf(hi.z); r[7] = f2bf(hi.w);
    return r;
}

// Block-cooperative W (fp32, k-major [64][64]) -> bf16 W^T tile in LDS.
__device__ __forceinline__ void stage_W(short (*Wt)[WST],
                                        const float* __restrict__ W, int t) {
    const int n  = t & 63;
    const int kb = (t >> 6) * 16;
    #pragma unroll
    for (int jj = 0; jj < 16; ++jj)
        Wt[n][kb + jj] = f2bf(W[(kb + jj) * 64 + n]);
}

__device__ __forceinline__ void layer_mfma_lds(bf16x8 a0, bf16x8 a1,
                                               const short (*Wt)[WST],
                                               const float* __restrict__ bias,
                                               int m, int quad, bool do_relu,
                                               f32x4 dout[4])
{
    #pragma unroll
    for (int nt = 0; nt < 4; ++nt) {
        const int n = nt * 16 + m;
        bf16x8 b0 = *(const bf16x8*)&Wt[n][quad * 8];
        bf16x8 b1 = *(const bf16x8*)&Wt[n][32 + quad * 8];
        f32x4 d = {0.f, 0.f, 0.f, 0.f};
        d = __builtin_amdgcn_mfma_f32_16x16x32_bf16(a0, b0, d, 0, 0, 0);
        d = __builtin_amdgcn_mfma_f32_16x16x32_bf16(a1, b1, d, 0, 0, 0);
        if (bias) {
            const float bb = bias[n];
            #pragma unroll
            for (int rg = 0; rg < 4; ++rg) d[rg] += bb;
        }
        if (do_relu) {
            #pragma unroll
            for (int rg = 0; rg < 4; ++rg) d[rg] = fmaxf(d[rg], 0.f);
        }
        dout[nt] = d;
    }
}

__device__ __forceinline__ void d_to_X(const f32x4 d[4], short (*X)[XST],
                                       int m, int quad) {
    #pragma unroll
    for (int nt = 0; nt < 4; ++nt)
        #pragma unroll
        for (int rg = 0; rg < 4; ++rg)
            X[quad * 4 + rg][nt * 16 + m] = f2bf(d[nt][rg]);
}

// LDS: union of the two phases' footprints. max = 66.6 KB -> 2 blocks/CU
// capacity (LDS 133 KB <= 160; VGPR capped at 256 by launch_bounds) so all
// 384 blocks are co-resident and the spin barrier below cannot deadlock.
union SMem {
    struct {
        short Wt[3][64][WST];       // 55296 B
        short Xs[4][16][XST];       // 10240 B
        float cms[4][16][4];        //  1024 B
    } q;
    struct {
        short al[IT][ABP];          // 24832 B (16B-aligned rows)
        float wmax[4][IT];
        float wsum[4][IT];
        float part3[4][IT][16];
    } a;
};

// Single-use grid barrier: agent-scope release/acquire. Counter pre-zeroed
// by hipMemsetAsync before every launch (workspace is re-poisoned each iter).
__device__ __forceinline__ void grid_barrier(unsigned* cnt) {
    __threadfence();               // agent-scope release of this thread's stores
    __syncthreads();
    if (threadIdx.x == 0) {
        __hip_atomic_fetch_add(cnt, 1u, __ATOMIC_RELEASE,
                               __HIP_MEMORY_SCOPE_AGENT);
        while (__hip_atomic_load(cnt, __ATOMIC_ACQUIRE,
                                 __HIP_MEMORY_SCOPE_AGENT) < GRID)
            __builtin_amdgcn_s_sleep(1);
    }
    __syncthreads();
    __threadfence();               // agent-scope acquire before workspace reads
}

// Fused kernel: phase 1 = qkv/coord MLPs -> workspace; grid barrier;
// phase 2 = attention + epilogues. One launch, no inter-kernel drain.
__global__ __launch_bounds__(256, 2) void fused_kernel(
    const float* __restrict__ h, const float* __restrict__ coord,
    const float* __restrict__ wq1, const float* __restrict__ bq1,
    const float* __restrict__ wq2, const float* __restrict__ bq2,
    const float* __restrict__ wk1, const float* __restrict__ bk1,
    const float* __restrict__ wk2, const float* __restrict__ bk2,
    const float* __restrict__ wv1, const float* __restrict__ bv1,
    const float* __restrict__ wv2, const float* __restrict__ bv2,
    const float* __restrict__ wc1, const float* __restrict__ bc1,
    const float* __restrict__ wc2,
    short* __restrict__ q_ws, short* __restrict__ k_ws,
    short* __restrict__ vT_ws, short* __restrict__ UT_ws,
    float* __restrict__ h_out, float* __restrict__ x_out,
    unsigned* __restrict__ bar)
{
    const int bb   = blockIdx.x;
    const int t    = threadIdx.x;
    const int lane = t & 63;
    const int w    = t >> 6;
    const int m    = lane & 15;
    const int quad = lane >> 4;

    __shared__ SMem sm;

    // ---- phase-2 INPUT-only prefetch (h, coord): issued before phase 1 so
    // HBM latency hides under the MLP work / barrier spin ----
    const int l2 = bb & 7;
    const int i0 = (bb >> 3) * IT;
    const int c  = 16 * w + m;
    float hpre[4];
    #pragma unroll
    for (int rg = 0; rg < 4; ++rg)
        hpre[rg] = h[((i0 + quad * 4 + rg) * 8 + l2) * 64 + c];
    float cdpre = 0.f;
    if (t < 192)
        cdpre = coord[((i0 + t / 12) * 8 + l2) * 12 + (t % 12)];

    // =========================== PHASE 1: MLPs ===========================
    if (bb < 288) {
        int chain, tb;
        if (bb < 96)       { chain = 2; tb = bb; }
        else if (bb < 192) { chain = 0; tb = bb - 96; }
        else               { chain = 1; tb = bb - 192; }
        const int rt = tb * 4 + w;      // 16-row tile, 0..383
        const int r0 = rt * 16;

        short (*X)[XST] = sm.q.Xs[w];

        // layer-1 A-frags straight from global h (fp32 -> bf16)
        bf16x8 a0, a1;
        {
            const float* hrow = h + (size_t)(r0 + m) * 64;
            a0 = pack8(*(const float4*)(hrow + quad * 8),
                       *(const float4*)(hrow + quad * 8 + 4));
            a1 = pack8(*(const float4*)(hrow + 32 + quad * 8),
                       *(const float4*)(hrow + 32 + quad * 8 + 4));
        }

        // chain-2 U-build coord operands, prefetched early
        float cpre[3];
        const int rowu = lane >> 2, kk = lane & 3;
        const int gu = r0 + rowu;
        if (chain == 2) {
            #pragma unroll
            for (int s = 0; s < 3; ++s)
                cpre[s] = coord[gu * 12 + kk * 3 + s];
        }

        // block-cooperative weight staging (4 waves share one chain)
        if (chain == 0)      { stage_W(sm.q.Wt[0], wq1, t); stage_W(sm.q.Wt[1], wq2, t); }
        else if (chain == 1) { stage_W(sm.q.Wt[0], wk1, t); stage_W(sm.q.Wt[1], wk2, t); }
        else                 { stage_W(sm.q.Wt[0], wv1, t); stage_W(sm.q.Wt[1], wv2, t);
                               stage_W(sm.q.Wt[2], wc1, t); }
        __syncthreads();

        f32x4 d[4];

        if (chain == 0) {
            layer_mfma_lds(a0, a1, sm.q.Wt[0], bq1, m, quad, true, d);
            d_to_X(d, X, m, quad);
            __builtin_amdgcn_wave_barrier();
            a0 = *(const bf16x8*)&X[m][quad * 8];
            a1 = *(const bf16x8*)&X[m][32 + quad * 8];
            layer_mfma_lds(a0, a1, sm.q.Wt[1], bq2, m, quad, true, d);
            #pragma unroll
            for (int nt = 0; nt < 4; ++nt)
                #pragma unroll
                for (int rg = 0; rg < 4; ++rg) {
                    const int g = r0 + quad * 4 + rg, i = g >> 3, l = g & 7;
                    q_ws[(l * NN + i) * 64 + nt * 16 + m] = f2bf(d[nt][rg]);
                }
        } else if (chain == 1) {
            layer_mfma_lds(a0, a1, sm.q.Wt[0], bk1, m, quad, true, d);
            d_to_X(d, X, m, quad);
            __builtin_amdgcn_wave_barrier();
            a0 = *(const bf16x8*)&X[m][quad * 8];
            a1 = *(const bf16x8*)&X[m][32 + quad * 8];
            layer_mfma_lds(a0, a1, sm.q.Wt[1], bk2, m, quad, true, d);
            #pragma unroll
            for (int nt = 0; nt < 4; ++nt)
                #pragma unroll
                for (int rg = 0; rg < 4; ++rg) {
                    const int g = r0 + quad * 4 + rg, i = g >> 3, l = g & 7;
                    k_ws[(l * NN + i) * 64 + nt * 16 + m] = f2bf(d[nt][rg]);
                }
        } else {
            layer_mfma_lds(a0, a1, sm.q.Wt[0], bv1, m, quad, true, d);
            d_to_X(d, X, m, quad);
            __builtin_amdgcn_wave_barrier();
            a0 = *(const bf16x8*)&X[m][quad * 8];
            a1 = *(const bf16x8*)&X[m][32 + quad * 8];
            layer_mfma_lds(a0, a1, sm.q.Wt[1], bv2, m, quad, true, d);
            // v: transposed stores + back into X (input to coord_mlp)
            #pragma unroll
            for (int nt = 0; nt < 4; ++nt)
                #pragma unroll
                for (int rg = 0; rg < 4; ++rg) {
                    const int g = r0 + quad * 4 + rg, i = g >> 3, l = g & 7;
                    vT_ws[((size_t)l * 64 + nt * 16 + m) * NN + i] = f2bf(d[nt][rg]);
                }
            d_to_X(d, X, m, quad);
            __builtin_amdgcn_wave_barrier();
            a0 = *(const bf16x8*)&X[m][quad * 8];
            a1 = *(const bf16x8*)&X[m][32 + quad * 8];
            layer_mfma_lds(a0, a1, sm.q.Wt[2], bc1, m, quad, true, d);
            d_to_X(d, X, m, quad);
            __builtin_amdgcn_wave_barrier();
            a0 = *(const bf16x8*)&X[m][quad * 8];
            a1 = *(const bf16x8*)&X[m][32 + quad * 8];
            // cmv = t1 @ wc2 (no bias/relu); wc2 is [64][4], cols m>=4 zero
            {
                bf16x8 b0, b1;
                #pragma unroll
                for (int j = 0; j < 8; ++j) {
                    b0[j] = (m < 4) ? f2bf(wc2[(quad * 8 + j) * 4 + m]) : (short)0;
                    b1[j] = (m < 4) ? f2bf(wc2[(32 + quad * 8 + j) * 4 + m]) : (short)0;
                }
                f32x4 dc = {0.f, 0.f, 0.f, 0.f};
                dc = __builtin_amdgcn_mfma_f32_16x16x32_bf16(a0, b0, dc, 0, 0, 0);
                dc = __builtin_amdgcn_mfma_f32_16x16x32_bf16(a1, b1, dc, 0, 0, 0);
                if (m < 4) {
                    #pragma unroll
                    for (int rg = 0; rg < 4; ++rg)
                        sm.q.cms[w][quad * 4 + rg][m] = dc[rg];
                }
            }
            __builtin_amdgcn_wave_barrier();
            {
                const float cv = sm.q.cms[w][rowu][kk];
                const int i = gu >> 3, l = gu & 7;
                UT_ws[((size_t)l * 16 + kk * 4 + 0) * NN + i] = f2bf(cv);
                #pragma unroll
                for (int seg = 1; seg < 4; ++seg) {
                    const float uval = cv * cpre[seg - 1];
                    UT_ws[((size_t)l * 16 + kk * 4 + seg) * NN + i] = f2bf(uval);
                }
            }
        }
    }

    // ======================= grid-wide barrier ==========================
    grid_barrier(bar);

    // ========================= PHASE 2: attn ============================
    const bf16x8 aq0 = *(const bf16x8*)&q_ws[((size_t)l2 * NN + i0 + m) * 64 + quad * 8];
    const bf16x8 aq1 = *(const bf16x8*)&q_ws[((size_t)l2 * NN + i0 + m) * 64 + 32 + quad * 8];

    f32x4 dsc[12];
    {
        const short* kl = k_ws + (size_t)l2 * NN * 64;
        #pragma unroll
        for (int nt = 0; nt < 12; ++nt) {
            const int jb = 192 * w + nt * 16;
            const short* krow = kl + (size_t)(jb + m) * 64;
            bf16x8 b0 = *(const bf16x8*)(krow + quad * 8);
            bf16x8 b1 = *(const bf16x8*)(krow + 32 + quad * 8);
            f32x4 d = {0.f, 0.f, 0.f, 0.f};
            d = __builtin_amdgcn_mfma_f32_16x16x32_bf16(aq0, b0, d, 0, 0, 0);
            d = __builtin_amdgcn_mfma_f32_16x16x32_bf16(aq1, b1, d, 0, 0, 0);
            dsc[nt] = d;
        }
    }

    float mx[4];
    #pragma unroll
    for (int rg = 0; rg < 4; ++rg) {
        float mm = dsc[0][rg];
        #pragma unroll
        for (int nt = 1; nt < 12; ++nt) mm = fmaxf(mm, dsc[nt][rg]);
        mm = fmaxf(mm, __shfl_xor(mm, 1, 64));
        mm = fmaxf(mm, __shfl_xor(mm, 2, 64));
        mm = fmaxf(mm, __shfl_xor(mm, 4, 64));
        mm = fmaxf(mm, __shfl_xor(mm, 8, 64));
        if (m == 0) sm.a.wmax[w][quad * 4 + rg] = mm;
    }
    __syncthreads();
    #pragma unroll
    for (int rg = 0; rg < 4; ++rg) {
        const int row = quad * 4 + rg;
        mx[rg] = fmaxf(fmaxf(sm.a.wmax[0][row], sm.a.wmax[1][row]),
                       fmaxf(sm.a.wmax[2][row], sm.a.wmax[3][row]));
    }

    // issue ALL vT/UT fragment loads now; they complete under the exp phase
    const short* vrow = vT_ws + ((size_t)l2 * 64 + 16 * w + m) * NN;
    const short* urow = UT_ws + ((size_t)l2 * 16 + m) * NN + 192 * w;
    bf16x8 vpre[24];
    bf16x8 upre[6];
    #pragma unroll
    for (int kt = 0; kt < 24; ++kt)
        vpre[kt] = *(const bf16x8*)(vrow + kt * 32 + quad * 8);
    #pragma unroll
    for (int kt = 0; kt < 6; ++kt)
        upre[kt] = *(const bf16x8*)(urow + kt * 32 + quad * 8);

    float sl[4] = {0.f, 0.f, 0.f, 0.f};
    #pragma unroll
    for (int nt = 0; nt < 12; ++nt) {
        const int jb = 192 * w + nt * 16;
        #pragma unroll
        for (int rg = 0; rg < 4; ++rg) {
            const float e = __expf(dsc[nt][rg] - mx[rg]);
            sl[rg] += e;
            sm.a.al[quad * 4 + rg][jb + m] = f2bf(e);
        }
    }
    #pragma unroll
    for (int rg = 0; rg < 4; ++rg) {
        float s = sl[rg];
        s += __shfl_xor(s, 1, 64);
        s += __shfl_xor(s, 2, 64);
        s += __shfl_xor(s, 4, 64);
        s += __shfl_xor(s, 8, 64);
        if (m == 0) sm.a.wsum[w][quad * 4 + rg] = s;
    }
    __syncthreads();

    {
        f32x4 acc0 = {0.f, 0.f, 0.f, 0.f};
        f32x4 acc1 = {0.f, 0.f, 0.f, 0.f};
        #pragma unroll
        for (int kt = 0; kt < 24; kt += 2) {
            const int ka = kt * 32, kb = ka + 32;
            bf16x8 a0 = *(const bf16x8*)&sm.a.al[m][ka + quad * 8];
            bf16x8 a1 = *(const bf16x8*)&sm.a.al[m][kb + quad * 8];
            acc0 = __builtin_amdgcn_mfma_f32_16x16x32_bf16(a0, vpre[kt], acc0, 0, 0, 0);
            acc1 = __builtin_amdgcn_mfma_f32_16x16x32_bf16(a1, vpre[kt + 1], acc1, 0, 0, 0);
        }
        #pragma unroll
        for (int rg = 0; rg < 4; ++rg) {
            const int i = quad * 4 + rg;
            const float ri = 1.f / (sm.a.wsum[0][i] + sm.a.wsum[1][i] +
                                    sm.a.wsum[2][i] + sm.a.wsum[3][i]);
            const int row = ((i0 + i) * 8 + l2) * 64 + c;
            h_out[row] = hpre[rg] + ri * (acc0[rg] + acc1[rg]);
        }
    }

    {
        f32x4 acc = {0.f, 0.f, 0.f, 0.f};
        #pragma unroll
        for (int kt = 0; kt < 6; ++kt) {
            const int k0 = kt * 32;
            bf16x8 a = *(const bf16x8*)&sm.a.al[m][192 * w + k0 + quad * 8];
            acc = __builtin_amdgcn_mfma_f32_16x16x32_bf16(a, upre[kt], acc, 0, 0, 0);
        }
        #pragma unroll
        for (int rg = 0; rg < 4; ++rg)
            sm.a.part3[w][quad * 4 + rg][m] = acc[rg];
    }
    __syncthreads();
    if (t < 192) {
        const int i4 = t / 12, kt = t % 12, k4 = kt / 3, s4 = kt % 3;
        const float ri = 1.f / (sm.a.wsum[0][i4] + sm.a.wsum[1][i4] +
                                sm.a.wsum[2][i4] + sm.a.wsum[3][i4]);
        const int uA = k4 * 4, uB = k4 * 4 + 1 + s4;
        const float sA = (sm.a.part3[0][i4][uA] + sm.a.part3[1][i4][uA] +
                          sm.a.part3[2][i4][uA] + sm.a.part3[3][i4][uA]) * ri;
        const float sB = (sm.a.part3[0][i4][uB] + sm.a.part3[1][i4][uB] +
                          sm.a.part3[2][i4][uB] + sm.a.part3[3][i4][uB]) * ri;
        const int idx = ((i0 + i4) * 8 + l2) * 12 + kt;
        x_out[idx] = cdpre + cdpre * sA - sB;
    }
}

extern "C" void kernel_launch(void* const* d_in, const int* in_sizes, int n_in,
                              void* d_out, int out_size, void* d_ws, size_t ws_size,
                              hipStream_t stream) {
    const float* h     = (const float*)d_in[0];
    const float* coord = (const float*)d_in[1];

    float* h_out = (float*)d_out;
    float* x_out = h_out + NN * LL * HH;     // 393216 floats

    short* q_ws  = (short*)d_ws;             // [L][N][64] bf16
    short* k_ws  = q_ws + NN * LL * HH;      // [L][N][64] bf16
    short* vT_ws = k_ws + NN * LL * HH;      // [L][64][N] bf16
    short* UT_ws = vT_ws + NN * LL * HH;     // [L][16][N] bf16

    // barrier counter at the workspace tail; workspace is re-poisoned each
    // iteration, so re-zero it every launch (memset node is capturable)
    unsigned* bar = (unsigned*)((char*)d_ws + ws_size - 256);
    hipMemsetAsync((void*)bar, 0, 256, stream);

    fused_kernel<<<GRID, 256, 0, stream>>>(
        h, coord,
        (const float*)d_in[2],  (const float*)d_in[3],
        (const float*)d_in[4],  (const float*)d_in[5],
        (const float*)d_in[6],  (const float*)d_in[7],
        (const float*)d_in[8],  (const float*)d_in[9],
        (const float*)d_in[10], (const float*)d_in[11],
        (const float*)d_in[12], (const float*)d_in[13],
        (const float*)d_in[14], (const float*)d_in[15],
        (const float*)d_in[16],
        q_ws, k_ws, vT_ws, UT_ws, h_out, x_out, bar);
}

// Round 3
// 143.578 us; speedup vs baseline: 1.9158x; 1.9158x over previous
//
#include <hip/hip_runtime.h>
#include <hip/hip_bf16.h>

#define NN 768
#define LL 8
#define HH 64
#define IT 16     // attn i-tile
#define ABP 776   // bf16 alpha row stride (shorts); 1552 B, 16B-aligned
#define XST 80    // qkv LDS X-tile row stride in shorts (160 B, 16B-aligned)
#define WST 72    // staged-W LDS row stride in shorts (144 B = 9*16, 16B-aligned)
#define GRID 384

typedef __attribute__((ext_vector_type(8))) short bf16x8;
typedef __attribute__((ext_vector_type(4))) float f32x4;

__device__ __forceinline__ short f2bf(float x) {
    union { __hip_bfloat16 h; short s; } u;
    u.h = __float2bfloat16(x);
    return u.s;
}

__device__ __forceinline__ bf16x8 pack8(float4 lo, float4 hi) {
    bf16x8 r;
    r[0] = f2bf(lo.x); r[1] = f2bf(lo.y); r[2] = f2bf(lo.z); r[3] = f2bf(lo.w);
    r[4] = f2bf(hi.x); r[5] = f2bf(hi.y); r[6] = f2bf(hi.z); r[7] = f2bf(hi.w);
    return r;
}

// Block-cooperative W (fp32, k-major [64][64]) -> bf16 W^T tile in LDS.
__device__ __forceinline__ void stage_W(short (*Wt)[WST],
                                        const float* __restrict__ W, int t) {
    const int n  = t & 63;
    const int kb = (t >> 6) * 16;
    #pragma unroll
    for (int jj = 0; jj < 16; ++jj)
        Wt[n][kb + jj] = f2bf(W[(kb + jj) * 64 + n]);
}

__device__ __forceinline__ void layer_mfma_lds(bf16x8 a0, bf16x8 a1,
                                               const short (*Wt)[WST],
                                               const float* __restrict__ bias,
                                               int m, int quad, bool do_relu,
                                               f32x4 dout[4])
{
    #pragma unroll
    for (int nt = 0; nt < 4; ++nt) {
        const int n = nt * 16 + m;
        bf16x8 b0 = *(const bf16x8*)&Wt[n][quad * 8];
        bf16x8 b1 = *(const bf16x8*)&Wt[n][32 + quad * 8];
        f32x4 d = {0.f, 0.f, 0.f, 0.f};
        d = __builtin_amdgcn_mfma_f32_16x16x32_bf16(a0, b0, d, 0, 0, 0);
        d = __builtin_amdgcn_mfma_f32_16x16x32_bf16(a1, b1, d, 0, 0, 0);
        if (bias) {
            const float bb = bias[n];
            #pragma unroll
            for (int rg = 0; rg < 4; ++rg) d[rg] += bb;
        }
        if (do_relu) {
            #pragma unroll
            for (int rg = 0; rg < 4; ++rg) d[rg] = fmaxf(d[rg], 0.f);
        }
        dout[nt] = d;
    }
}

__device__ __forceinline__ void d_to_X(const f32x4 d[4], short (*X)[XST],
                                       int m, int quad) {
    #pragma unroll
    for (int nt = 0; nt < 4; ++nt)
        #pragma unroll
        for (int rg = 0; rg < 4; ++rg)
            X[quad * 4 + rg][nt * 16 + m] = f2bf(d[nt][rg]);
}

// LDS union of the two phases (38912 B -> 4 blocks/CU by LDS; VGPR ~96 ->
// all 384 blocks co-resident on 256 CUs, so the spin barrier cannot deadlock).
union SMem {
    struct {
        short Wt[3][64][WST];
        short Xs[4][16][XST];
        float cms[4][16][4];
    } q;
    struct {
        short al[IT][ABP];
        float wmax[4][IT];
        float wsum[4][IT];
        float part3[4][IT][16];
    } a;
};

// Grid barrier, cooperative-groups idiom. Cost per block: one release
// fetch_add (single buffer_wbl2 -- __syncthreads already drained all waves'
// stores to L2 via vmcnt(0)), a RELAXED poll loop with s_sleep backoff
// (NO cache-maintenance ops per iteration -- this was round-2's 180 us bug:
// acquire-per-poll emitted buffer_inv every iteration from 384 pollers),
// then ONE acquire load (single buffer_inv; all 4 waves share this CU's L1,
// and the trailing __syncthreads orders it before their workspace reads).
__device__ __forceinline__ void grid_barrier(unsigned* cnt) {
    __syncthreads();
    if (threadIdx.x == 0) {
        __hip_atomic_fetch_add(cnt, 1u, __ATOMIC_RELEASE,
                               __HIP_MEMORY_SCOPE_AGENT);
        while (__hip_atomic_load(cnt, __ATOMIC_RELAXED,
                                 __HIP_MEMORY_SCOPE_AGENT) < GRID)
            __builtin_amdgcn_s_sleep(8);
        (void)__hip_atomic_load(cnt, __ATOMIC_ACQUIRE,
                                __HIP_MEMORY_SCOPE_AGENT);
    }
    __syncthreads();
}

__global__ __launch_bounds__(256, 2) void fused_kernel(
    const float* __restrict__ h, const float* __restrict__ coord,
    const float* __restrict__ wq1, const float* __restrict__ bq1,
    const float* __restrict__ wq2, const float* __restrict__ bq2,
    const float* __restrict__ wk1, const float* __restrict__ bk1,
    const float* __restrict__ wk2, const float* __restrict__ bk2,
    const float* __restrict__ wv1, const float* __restrict__ bv1,
    const float* __restrict__ wv2, const float* __restrict__ bv2,
    const float* __restrict__ wc1, const float* __restrict__ bc1,
    const float* __restrict__ wc2,
    short* __restrict__ q_ws, short* __restrict__ k_ws,
    short* __restrict__ vT_ws, short* __restrict__ UT_ws,
    float* __restrict__ h_out, float* __restrict__ x_out,
    unsigned* __restrict__ bar)
{
    const int bb   = blockIdx.x;
    const int t    = threadIdx.x;
    const int lane = t & 63;
    const int w    = t >> 6;
    const int m    = lane & 15;
    const int quad = lane >> 4;

    __shared__ SMem sm;

    // ---- phase-2 INPUT-only prefetch (h, coord): registers survive the
    // barrier; HBM latency hides under phase 1 / the spin ----
    const int l2 = bb & 7;
    const int i0 = (bb >> 3) * IT;
    const int c  = 16 * w + m;
    float hpre[4];
    #pragma unroll
    for (int rg = 0; rg < 4; ++rg)
        hpre[rg] = h[((i0 + quad * 4 + rg) * 8 + l2) * 64 + c];
    float cdpre = 0.f;
    if (t < 192)
        cdpre = coord[((i0 + t / 12) * 8 + l2) * 12 + (t % 12)];

    // =========================== PHASE 1: MLPs ===========================
    if (bb < 288) {
        int chain, tb;
        if (bb < 96)       { chain = 2; tb = bb; }
        else if (bb < 192) { chain = 0; tb = bb - 96; }
        else               { chain = 1; tb = bb - 192; }
        const int rt = tb * 4 + w;      // 16-row tile, 0..383
        const int r0 = rt * 16;

        short (*X)[XST] = sm.q.Xs[w];

        bf16x8 a0, a1;
        {
            const float* hrow = h + (size_t)(r0 + m) * 64;
            a0 = pack8(*(const float4*)(hrow + quad * 8),
                       *(const float4*)(hrow + quad * 8 + 4));
            a1 = pack8(*(const float4*)(hrow + 32 + quad * 8),
                       *(const float4*)(hrow + 32 + quad * 8 + 4));
        }

        float cpre[3];
        const int rowu = lane >> 2, kk = lane & 3;
        const int gu = r0 + rowu;
        if (chain == 2) {
            #pragma unroll
            for (int s = 0; s < 3; ++s)
                cpre[s] = coord[gu * 12 + kk * 3 + s];
        }

        if (chain == 0)      { stage_W(sm.q.Wt[0], wq1, t); stage_W(sm.q.Wt[1], wq2, t); }
        else if (chain == 1) { stage_W(sm.q.Wt[0], wk1, t); stage_W(sm.q.Wt[1], wk2, t); }
        else                 { stage_W(sm.q.Wt[0], wv1, t); stage_W(sm.q.Wt[1], wv2, t);
                               stage_W(sm.q.Wt[2], wc1, t); }
        __syncthreads();

        f32x4 d[4];

        if (chain == 0) {
            layer_mfma_lds(a0, a1, sm.q.Wt[0], bq1, m, quad, true, d);
            d_to_X(d, X, m, quad);
            __builtin_amdgcn_wave_barrier();
            a0 = *(const bf16x8*)&X[m][quad * 8];
            a1 = *(const bf16x8*)&X[m][32 + quad * 8];
            layer_mfma_lds(a0, a1, sm.q.Wt[1], bq2, m, quad, true, d);
            #pragma unroll
            for (int nt = 0; nt < 4; ++nt)
                #pragma unroll
                for (int rg = 0; rg < 4; ++rg) {
                    const int g = r0 + quad * 4 + rg, i = g >> 3, l = g & 7;
                    q_ws[(l * NN + i) * 64 + nt * 16 + m] = f2bf(d[nt][rg]);
                }
        } else if (chain == 1) {
            layer_mfma_lds(a0, a1, sm.q.Wt[0], bk1, m, quad, true, d);
            d_to_X(d, X, m, quad);
            __builtin_amdgcn_wave_barrier();
            a0 = *(const bf16x8*)&X[m][quad * 8];
            a1 = *(const bf16x8*)&X[m][32 + quad * 8];
            layer_mfma_lds(a0, a1, sm.q.Wt[1], bk2, m, quad, true, d);
            #pragma unroll
            for (int nt = 0; nt < 4; ++nt)
                #pragma unroll
                for (int rg = 0; rg < 4; ++rg) {
                    const int g = r0 + quad * 4 + rg, i = g >> 3, l = g & 7;
                    k_ws[(l * NN + i) * 64 + nt * 16 + m] = f2bf(d[nt][rg]);
                }
        } else {
            layer_mfma_lds(a0, a1, sm.q.Wt[0], bv1, m, quad, true, d);
            d_to_X(d, X, m, quad);
            __builtin_amdgcn_wave_barrier();
            a0 = *(const bf16x8*)&X[m][quad * 8];
            a1 = *(const bf16x8*)&X[m][32 + quad * 8];
            layer_mfma_lds(a0, a1, sm.q.Wt[1], bv2, m, quad, true, d);
            #pragma unroll
            for (int nt = 0; nt < 4; ++nt)
                #pragma unroll
                for (int rg = 0; rg < 4; ++rg) {
                    const int g = r0 + quad * 4 + rg, i = g >> 3, l = g & 7;
                    vT_ws[((size_t)l * 64 + nt * 16 + m) * NN + i] = f2bf(d[nt][rg]);
                }
            d_to_X(d, X, m, quad);
            __builtin_amdgcn_wave_barrier();
            a0 = *(const bf16x8*)&X[m][quad * 8];
            a1 = *(const bf16x8*)&X[m][32 + quad * 8];
            layer_mfma_lds(a0, a1, sm.q.Wt[2], bc1, m, quad, true, d);
            d_to_X(d, X, m, quad);
            __builtin_amdgcn_wave_barrier();
            a0 = *(const bf16x8*)&X[m][quad * 8];
            a1 = *(const bf16x8*)&X[m][32 + quad * 8];
            {
                bf16x8 b0, b1;
                #pragma unroll
                for (int j = 0; j < 8; ++j) {
                    b0[j] = (m < 4) ? f2bf(wc2[(quad * 8 + j) * 4 + m]) : (short)0;
                    b1[j] = (m < 4) ? f2bf(wc2[(32 + quad * 8 + j) * 4 + m]) : (short)0;
                }
                f32x4 dc = {0.f, 0.f, 0.f, 0.f};
                dc = __builtin_amdgcn_mfma_f32_16x16x32_bf16(a0, b0, dc, 0, 0, 0);
                dc = __builtin_amdgcn_mfma_f32_16x16x32_bf16(a1, b1, dc, 0, 0, 0);
                if (m < 4) {
                    #pragma unroll
                    for (int rg = 0; rg < 4; ++rg)
                        sm.q.cms[w][quad * 4 + rg][m] = dc[rg];
                }
            }
            __builtin_amdgcn_wave_barrier();
            {
                const float cv = sm.q.cms[w][rowu][kk];
                const int i = gu >> 3, l = gu & 7;
                UT_ws[((size_t)l * 16 + kk * 4 + 0) * NN + i] = f2bf(cv);
                #pragma unroll
                for (int seg = 1; seg < 4; ++seg) {
                    const float uval = cv * cpre[seg - 1];
                    UT_ws[((size_t)l * 16 + kk * 4 + seg) * NN + i] = f2bf(uval);
                }
            }
        }
    }

    // ======================= grid-wide barrier ==========================
    grid_barrier(bar);

    // ========================= PHASE 2: attn ============================
    const bf16x8 aq0 = *(const bf16x8*)&q_ws[((size_t)l2 * NN + i0 + m) * 64 + quad * 8];
    const bf16x8 aq1 = *(const bf16x8*)&q_ws[((size_t)l2 * NN + i0 + m) * 64 + 32 + quad * 8];

    f32x4 dsc[12];
    {
        const short* kl = k_ws + (size_t)l2 * NN * 64;
        #pragma unroll
        for (int nt = 0; nt < 12; ++nt) {
            const int jb = 192 * w + nt * 16;
            const short* krow = kl + (size_t)(jb + m) * 64;
            bf16x8 b0 = *(const bf16x8*)(krow + quad * 8);
            bf16x8 b1 = *(const bf16x8*)(krow + 32 + quad * 8);
            f32x4 d = {0.f, 0.f, 0.f, 0.f};
            d = __builtin_amdgcn_mfma_f32_16x16x32_bf16(aq0, b0, d, 0, 0, 0);
            d = __builtin_amdgcn_mfma_f32_16x16x32_bf16(aq1, b1, d, 0, 0, 0);
            dsc[nt] = d;
        }
    }

    float mx[4];
    #pragma unroll
    for (int rg = 0; rg < 4; ++rg) {
        float mm = dsc[0][rg];
        #pragma unroll
        for (int nt = 1; nt < 12; ++nt) mm = fmaxf(mm, dsc[nt][rg]);
        mm = fmaxf(mm, __shfl_xor(mm, 1, 64));
        mm = fmaxf(mm, __shfl_xor(mm, 2, 64));
        mm = fmaxf(mm, __shfl_xor(mm, 4, 64));
        mm = fmaxf(mm, __shfl_xor(mm, 8, 64));
        if (m == 0) sm.a.wmax[w][quad * 4 + rg] = mm;
    }
    __syncthreads();
    #pragma unroll
    for (int rg = 0; rg < 4; ++rg) {
        const int row = quad * 4 + rg;
        mx[rg] = fmaxf(fmaxf(sm.a.wmax[0][row], sm.a.wmax[1][row]),
                       fmaxf(sm.a.wmax[2][row], sm.a.wmax[3][row]));
    }

    // issue ALL vT/UT fragment loads now; they complete under the exp phase
    const short* vrow = vT_ws + ((size_t)l2 * 64 + 16 * w + m) * NN;
    const short* urow = UT_ws + ((size_t)l2 * 16 + m) * NN + 192 * w;
    bf16x8 vpre[24];
    bf16x8 upre[6];
    #pragma unroll
    for (int kt = 0; kt < 24; ++kt)
        vpre[kt] = *(const bf16x8*)(vrow + kt * 32 + quad * 8);
    #pragma unroll
    for (int kt = 0; kt < 6; ++kt)
        upre[kt] = *(const bf16x8*)(urow + kt * 32 + quad * 8);

    float sl[4] = {0.f, 0.f, 0.f, 0.f};
    #pragma unroll
    for (int nt = 0; nt < 12; ++nt) {
        const int jb = 192 * w + nt * 16;
        #pragma unroll
        for (int rg = 0; rg < 4; ++rg) {
            const float e = __expf(dsc[nt][rg] - mx[rg]);
            sl[rg] += e;
            sm.a.al[quad * 4 + rg][jb + m] = f2bf(e);
        }
    }
    #pragma unroll
    for (int rg = 0; rg < 4; ++rg) {
        float s = sl[rg];
        s += __shfl_xor(s, 1, 64);
        s += __shfl_xor(s, 2, 64);
        s += __shfl_xor(s, 4, 64);
        s += __shfl_xor(s, 8, 64);
        if (m == 0) sm.a.wsum[w][quad * 4 + rg] = s;
    }
    __syncthreads();

    {
        f32x4 acc0 = {0.f, 0.f, 0.f, 0.f};
        f32x4 acc1 = {0.f, 0.f, 0.f, 0.f};
        #pragma unroll
        for (int kt = 0; kt < 24; kt += 2) {
            const int ka = kt * 32, kb = ka + 32;
            bf16x8 a0 = *(const bf16x8*)&sm.a.al[m][ka + quad * 8];
            bf16x8 a1 = *(const bf16x8*)&sm.a.al[m][kb + quad * 8];
            acc0 = __builtin_amdgcn_mfma_f32_16x16x32_bf16(a0, vpre[kt], acc0, 0, 0, 0);
            acc1 = __builtin_amdgcn_mfma_f32_16x16x32_bf16(a1, vpre[kt + 1], acc1, 0, 0, 0);
        }
        #pragma unroll
        for (int rg = 0; rg < 4; ++rg) {
            const int i = quad * 4 + rg;
            const float ri = 1.f / (sm.a.wsum[0][i] + sm.a.wsum[1][i] +
                                    sm.a.wsum[2][i] + sm.a.wsum[3][i]);
            const int row = ((i0 + i) * 8 + l2) * 64 + c;
            h_out[row] = hpre[rg] + ri * (acc0[rg] + acc1[rg]);
        }
    }

    {
        f32x4 acc = {0.f, 0.f, 0.f, 0.f};
        #pragma unroll
        for (int kt = 0; kt < 6; ++kt) {
            const int k0 = kt * 32;
            bf16x8 a = *(const bf16x8*)&sm.a.al[m][192 * w + k0 + quad * 8];
            acc = __builtin_amdgcn_mfma_f32_16x16x32_bf16(a, upre[kt], acc, 0, 0, 0);
        }
        #pragma unroll
        for (int rg = 0; rg < 4; ++rg)
            sm.a.part3[w][quad * 4 + rg][m] = acc[rg];
    }
    __syncthreads();
    if (t < 192) {
        const int i4 = t / 12, kt = t % 12, k4 = kt / 3, s4 = kt % 3;
        const float ri = 1.f / (sm.a.wsum[0][i4] + sm.a.wsum[1][i4] +
                                sm.a.wsum[2][i4] + sm.a.wsum[3][i4]);
        const int uA = k4 * 4, uB = k4 * 4 + 1 + s4;
        const float sA = (sm.a.part3[0][i4][uA] + sm.a.part3[1][i4][uA] +
                          sm.a.part3[2][i4][uA] + sm.a.part3[3][i4][uA]) * ri;
        const float sB = (sm.a.part3[0][i4][uB] + sm.a.part3[1][i4][uB] +
                          sm.a.part3[2][i4][uB] + sm.a.part3[3][i4][uB]) * ri;
        const int idx = ((i0 + i4) * 8 + l2) * 12 + kt;
        x_out[idx] = cdpre + cdpre * sA - sB;
    }
}

extern "C" void kernel_launch(void* const* d_in, const int* in_sizes, int n_in,
                              void* d_out, int out_size, void* d_ws, size_t ws_size,
                              hipStream_t stream) {
    const float* h     = (const float*)d_in[0];
    const float* coord = (const float*)d_in[1];

    float* h_out = (float*)d_out;
    float* x_out = h_out + NN * LL * HH;     // 393216 floats

    short* q_ws  = (short*)d_ws;             // [L][N][64] bf16
    short* k_ws  = q_ws + NN * LL * HH;      // [L][N][64] bf16
    short* vT_ws = k_ws + NN * LL * HH;      // [L][64][N] bf16
    short* UT_ws = vT_ws + NN * LL * HH;     // [L][16][N] bf16

    // barrier counter at the workspace tail; workspace is re-poisoned each
    // iteration, so re-zero it every launch (memset node is capturable)
    unsigned* bar = (unsigned*)((char*)d_ws + ws_size - 256);
    hipMemsetAsync((void*)bar, 0, 256, stream);

    fused_kernel<<<GRID, 256, 0, stream>>>(
        h, coord,
        (const float*)d_in[2],  (const float*)d_in[3],
        (const float*)d_in[4],  (const float*)d_in[5],
        (const float*)d_in[6],  (const float*)d_in[7],
        (const float*)d_in[8],  (const float*)d_in[9],
        (const float*)d_in[10], (const float*)d_in[11],
        (const float*)d_in[12], (const float*)d_in[13],
        (const float*)d_in[14], (const float*)d_in[15],
        (const float*)d_in[16],
        q_ws, k_ws, vT_ws, UT_ws, h_out, x_out, bar);
}

// Round 4
// 127.921 us; speedup vs baseline: 2.1503x; 1.1224x over previous
//
#include <hip/hip_runtime.h>
#include <hip/hip_bf16.h>

#define NN 768
#define LL 8
#define HH 64
#define IT 16     // attn i-tile
#define ABP 776   // bf16 alpha row stride (shorts); 1552 B, 16B-aligned
#define XST 80    // qkv LDS X-tile row stride in shorts (160 B, 16B-aligned)
#define WST 72    // staged-W LDS row stride in shorts (144 B = 9*16, 16B-aligned)
#define GRID 384

typedef __attribute__((ext_vector_type(8))) short bf16x8;
typedef __attribute__((ext_vector_type(4))) float f32x4;

__device__ __forceinline__ short f2bf(float x) {
    union { __hip_bfloat16 h; short s; } u;
    u.h = __float2bfloat16(x);
    return u.s;
}

__device__ __forceinline__ bf16x8 pack8(float4 lo, float4 hi) {
    bf16x8 r;
    r[0] = f2bf(lo.x); r[1] = f2bf(lo.y); r[2] = f2bf(lo.z); r[3] = f2bf(lo.w);
    r[4] = f2bf(hi.x); r[5] = f2bf(hi.y); r[6] = f2bf(hi.z); r[7] = f2bf(hi.w);
    return r;
}

// Block-cooperative W (fp32, k-major [64][64]) -> bf16 W^T tile in LDS.
__device__ __forceinline__ void stage_W(short (*Wt)[WST],
                                        const float* __restrict__ W, int t) {
    const int n  = t & 63;
    const int kb = (t >> 6) * 16;
    #pragma unroll
    for (int jj = 0; jj < 16; ++jj)
        Wt[n][kb + jj] = f2bf(W[(kb + jj) * 64 + n]);
}

__device__ __forceinline__ void layer_mfma_lds(bf16x8 a0, bf16x8 a1,
                                               const short (*Wt)[WST],
                                               const float* __restrict__ bias,
                                               int m, int quad, bool do_relu,
                                               f32x4 dout[4])
{
    #pragma unroll
    for (int nt = 0; nt < 4; ++nt) {
        const int n = nt * 16 + m;
        bf16x8 b0 = *(const bf16x8*)&Wt[n][quad * 8];
        bf16x8 b1 = *(const bf16x8*)&Wt[n][32 + quad * 8];
        f32x4 d = {0.f, 0.f, 0.f, 0.f};
        d = __builtin_amdgcn_mfma_f32_16x16x32_bf16(a0, b0, d, 0, 0, 0);
        d = __builtin_amdgcn_mfma_f32_16x16x32_bf16(a1, b1, d, 0, 0, 0);
        if (bias) {
            const float bb = bias[n];
            #pragma unroll
            for (int rg = 0; rg < 4; ++rg) d[rg] += bb;
        }
        if (do_relu) {
            #pragma unroll
            for (int rg = 0; rg < 4; ++rg) d[rg] = fmaxf(d[rg], 0.f);
        }
        dout[nt] = d;
    }
}

__device__ __forceinline__ void d_to_X(const f32x4 d[4], short (*X)[XST],
                                       int m, int quad) {
    #pragma unroll
    for (int nt = 0; nt < 4; ++nt)
        #pragma unroll
        for (int rg = 0; rg < 4; ++rg)
            X[quad * 4 + rg][nt * 16 + m] = f2bf(d[nt][rg]);
}

// LDS union of the two phases (38912 B -> 4 blocks/CU by LDS; VGPR ~96 ->
// all 384 blocks co-resident on 256 CUs, so the spin barrier cannot deadlock).
union SMem {
    struct {
        short Wt[3][64][WST];
        short Xs[4][16][XST];
        float cms[4][16][4];
    } q;
    struct {
        short al[IT][ABP];
        float wmax[4][IT];
        float wsum[4][IT];
        float part3[4][IT][16];
    } a;
};

// Grid barrier, two-line design.
//   Line A (cnt):  one fetch_add(ACQ_REL) per block. RMW-only traffic --
//       no reader storm (round-3 bug: pollers spun on THIS line, and the
//       relaxed sc1 poll reads serialized against the atomic stream at the
//       coherence point, queueing the arrivals themselves -> ~50 us idle).
//   Line B (flag, +256 B): set once by the 384th arriver (store RELEASE);
//       everyone polls it RELAXED with s_sleep(32) backoff (clean read-only
//       line at the MALL), then one ACQUIRE load to pull in all published
//       workspace stores.
__device__ __forceinline__ void grid_barrier(unsigned* cnt, unsigned* flag) {
    __syncthreads();
    if (threadIdx.x == 0) {
        const unsigned prev =
            __hip_atomic_fetch_add(cnt, 1u, __ATOMIC_ACQ_REL,
                                   __HIP_MEMORY_SCOPE_AGENT);
        if (prev == GRID - 1) {
            __hip_atomic_store(flag, 1u, __ATOMIC_RELEASE,
                               __HIP_MEMORY_SCOPE_AGENT);
        } else {
            while (__hip_atomic_load(flag, __ATOMIC_RELAXED,
                                     __HIP_MEMORY_SCOPE_AGENT) == 0u)
                __builtin_amdgcn_s_sleep(32);
            (void)__hip_atomic_load(flag, __ATOMIC_ACQUIRE,
                                    __HIP_MEMORY_SCOPE_AGENT);
        }
    }
    __syncthreads();
}

__global__ __launch_bounds__(256, 2) void fused_kernel(
    const float* __restrict__ h, const float* __restrict__ coord,
    const float* __restrict__ wq1, const float* __restrict__ bq1,
    const float* __restrict__ wq2, const float* __restrict__ bq2,
    const float* __restrict__ wk1, const float* __restrict__ bk1,
    const float* __restrict__ wk2, const float* __restrict__ bk2,
    const float* __restrict__ wv1, const float* __restrict__ bv1,
    const float* __restrict__ wv2, const float* __restrict__ bv2,
    const float* __restrict__ wc1, const float* __restrict__ bc1,
    const float* __restrict__ wc2,
    short* __restrict__ q_ws, short* __restrict__ k_ws,
    short* __restrict__ vT_ws, short* __restrict__ UT_ws,
    float* __restrict__ h_out, float* __restrict__ x_out,
    unsigned* __restrict__ bar)
{
    const int bb   = blockIdx.x;
    const int t    = threadIdx.x;
    const int lane = t & 63;
    const int w    = t >> 6;
    const int m    = lane & 15;
    const int quad = lane >> 4;

    __shared__ SMem sm;

    // ---- phase-2 INPUT-only prefetch (h, coord): registers survive the
    // barrier; HBM latency hides under phase 1 / the spin ----
    const int l2 = bb & 7;
    const int i0 = (bb >> 3) * IT;
    const int c  = 16 * w + m;
    float hpre[4];
    #pragma unroll
    for (int rg = 0; rg < 4; ++rg)
        hpre[rg] = h[((i0 + quad * 4 + rg) * 8 + l2) * 64 + c];
    float cdpre = 0.f;
    if (t < 192)
        cdpre = coord[((i0 + t / 12) * 8 + l2) * 12 + (t % 12)];

    // =========================== PHASE 1: MLPs ===========================
    if (bb < 288) {
        int chain, tb;
        if (bb < 96)       { chain = 2; tb = bb; }
        else if (bb < 192) { chain = 0; tb = bb - 96; }
        else               { chain = 1; tb = bb - 192; }
        const int rt = tb * 4 + w;      // 16-row tile, 0..383
        const int r0 = rt * 16;

        short (*X)[XST] = sm.q.Xs[w];

        bf16x8 a0, a1;
        {
            const float* hrow = h + (size_t)(r0 + m) * 64;
            a0 = pack8(*(const float4*)(hrow + quad * 8),
                       *(const float4*)(hrow + quad * 8 + 4));
            a1 = pack8(*(const float4*)(hrow + 32 + quad * 8),
                       *(const float4*)(hrow + 32 + quad * 8 + 4));
        }

        float cpre[3];
        const int rowu = lane >> 2, kk = lane & 3;
        const int gu = r0 + rowu;
        if (chain == 2) {
            #pragma unroll
            for (int s = 0; s < 3; ++s)
                cpre[s] = coord[gu * 12 + kk * 3 + s];
        }

        if (chain == 0)      { stage_W(sm.q.Wt[0], wq1, t); stage_W(sm.q.Wt[1], wq2, t); }
        else if (chain == 1) { stage_W(sm.q.Wt[0], wk1, t); stage_W(sm.q.Wt[1], wk2, t); }
        else                 { stage_W(sm.q.Wt[0], wv1, t); stage_W(sm.q.Wt[1], wv2, t);
                               stage_W(sm.q.Wt[2], wc1, t); }
        __syncthreads();

        f32x4 d[4];

        if (chain == 0) {
            layer_mfma_lds(a0, a1, sm.q.Wt[0], bq1, m, quad, true, d);
            d_to_X(d, X, m, quad);
            __builtin_amdgcn_wave_barrier();
            a0 = *(const bf16x8*)&X[m][quad * 8];
            a1 = *(const bf16x8*)&X[m][32 + quad * 8];
            layer_mfma_lds(a0, a1, sm.q.Wt[1], bq2, m, quad, true, d);
            #pragma unroll
            for (int nt = 0; nt < 4; ++nt)
                #pragma unroll
                for (int rg = 0; rg < 4; ++rg) {
                    const int g = r0 + quad * 4 + rg, i = g >> 3, l = g & 7;
                    q_ws[(l * NN + i) * 64 + nt * 16 + m] = f2bf(d[nt][rg]);
                }
        } else if (chain == 1) {
            layer_mfma_lds(a0, a1, sm.q.Wt[0], bk1, m, quad, true, d);
            d_to_X(d, X, m, quad);
            __builtin_amdgcn_wave_barrier();
            a0 = *(const bf16x8*)&X[m][quad * 8];
            a1 = *(const bf16x8*)&X[m][32 + quad * 8];
            layer_mfma_lds(a0, a1, sm.q.Wt[1], bk2, m, quad, true, d);
            #pragma unroll
            for (int nt = 0; nt < 4; ++nt)
                #pragma unroll
                for (int rg = 0; rg < 4; ++rg) {
                    const int g = r0 + quad * 4 + rg, i = g >> 3, l = g & 7;
                    k_ws[(l * NN + i) * 64 + nt * 16 + m] = f2bf(d[nt][rg]);
                }
        } else {
            layer_mfma_lds(a0, a1, sm.q.Wt[0], bv1, m, quad, true, d);
            d_to_X(d, X, m, quad);
            __builtin_amdgcn_wave_barrier();
            a0 = *(const bf16x8*)&X[m][quad * 8];
            a1 = *(const bf16x8*)&X[m][32 + quad * 8];
            layer_mfma_lds(a0, a1, sm.q.Wt[1], bv2, m, quad, true, d);
            #pragma unroll
            for (int nt = 0; nt < 4; ++nt)
                #pragma unroll
                for (int rg = 0; rg < 4; ++rg) {
                    const int g = r0 + quad * 4 + rg, i = g >> 3, l = g & 7;
                    vT_ws[((size_t)l * 64 + nt * 16 + m) * NN + i] = f2bf(d[nt][rg]);
                }
            d_to_X(d, X, m, quad);
            __builtin_amdgcn_wave_barrier();
            a0 = *(const bf16x8*)&X[m][quad * 8];
            a1 = *(const bf16x8*)&X[m][32 + quad * 8];
            layer_mfma_lds(a0, a1, sm.q.Wt[2], bc1, m, quad, true, d);
            d_to_X(d, X, m, quad);
            __builtin_amdgcn_wave_barrier();
            a0 = *(const bf16x8*)&X[m][quad * 8];
            a1 = *(const bf16x8*)&X[m][32 + quad * 8];
            {
                bf16x8 b0, b1;
                #pragma unroll
                for (int j = 0; j < 8; ++j) {
                    b0[j] = (m < 4) ? f2bf(wc2[(quad * 8 + j) * 4 + m]) : (short)0;
                    b1[j] = (m < 4) ? f2bf(wc2[(32 + quad * 8 + j) * 4 + m]) : (short)0;
                }
                f32x4 dc = {0.f, 0.f, 0.f, 0.f};
                dc = __builtin_amdgcn_mfma_f32_16x16x32_bf16(a0, b0, dc, 0, 0, 0);
                dc = __builtin_amdgcn_mfma_f32_16x16x32_bf16(a1, b1, dc, 0, 0, 0);
                if (m < 4) {
                    #pragma unroll
                    for (int rg = 0; rg < 4; ++rg)
                        sm.q.cms[w][quad * 4 + rg][m] = dc[rg];
                }
            }
            __builtin_amdgcn_wave_barrier();
            {
                const float cv = sm.q.cms[w][rowu][kk];
                const int i = gu >> 3, l = gu & 7;
                UT_ws[((size_t)l * 16 + kk * 4 + 0) * NN + i] = f2bf(cv);
                #pragma unroll
                for (int seg = 1; seg < 4; ++seg) {
                    const float uval = cv * cpre[seg - 1];
                    UT_ws[((size_t)l * 16 + kk * 4 + seg) * NN + i] = f2bf(uval);
                }
            }
        }
    }

    // ======================= grid-wide barrier ==========================
    grid_barrier(bar, bar + 64);

    // ========================= PHASE 2: attn ============================
    const bf16x8 aq0 = *(const bf16x8*)&q_ws[((size_t)l2 * NN + i0 + m) * 64 + quad * 8];
    const bf16x8 aq1 = *(const bf16x8*)&q_ws[((size_t)l2 * NN + i0 + m) * 64 + 32 + quad * 8];

    f32x4 dsc[12];
    {
        const short* kl = k_ws + (size_t)l2 * NN * 64;
        #pragma unroll
        for (int nt = 0; nt < 12; ++nt) {
            const int jb = 192 * w + nt * 16;
            const short* krow = kl + (size_t)(jb + m) * 64;
            bf16x8 b0 = *(const bf16x8*)(krow + quad * 8);
            bf16x8 b1 = *(const bf16x8*)(krow + 32 + quad * 8);
            f32x4 d = {0.f, 0.f, 0.f, 0.f};
            d = __builtin_amdgcn_mfma_f32_16x16x32_bf16(aq0, b0, d, 0, 0, 0);
            d = __builtin_amdgcn_mfma_f32_16x16x32_bf16(aq1, b1, d, 0, 0, 0);
            dsc[nt] = d;
        }
    }

    float mx[4];
    #pragma unroll
    for (int rg = 0; rg < 4; ++rg) {
        float mm = dsc[0][rg];
        #pragma unroll
        for (int nt = 1; nt < 12; ++nt) mm = fmaxf(mm, dsc[nt][rg]);
        mm = fmaxf(mm, __shfl_xor(mm, 1, 64));
        mm = fmaxf(mm, __shfl_xor(mm, 2, 64));
        mm = fmaxf(mm, __shfl_xor(mm, 4, 64));
        mm = fmaxf(mm, __shfl_xor(mm, 8, 64));
        if (m == 0) sm.a.wmax[w][quad * 4 + rg] = mm;
    }
    __syncthreads();
    #pragma unroll
    for (int rg = 0; rg < 4; ++rg) {
        const int row = quad * 4 + rg;
        mx[rg] = fmaxf(fmaxf(sm.a.wmax[0][row], sm.a.wmax[1][row]),
                       fmaxf(sm.a.wmax[2][row], sm.a.wmax[3][row]));
    }

    // issue ALL vT/UT fragment loads now; they complete under the exp phase
    const short* vrow = vT_ws + ((size_t)l2 * 64 + 16 * w + m) * NN;
    const short* urow = UT_ws + ((size_t)l2 * 16 + m) * NN + 192 * w;
    bf16x8 vpre[24];
    bf16x8 upre[6];
    #pragma unroll
    for (int kt = 0; kt < 24; ++kt)
        vpre[kt] = *(const bf16x8*)(vrow + kt * 32 + quad * 8);
    #pragma unroll
    for (int kt = 0; kt < 6; ++kt)
        upre[kt] = *(const bf16x8*)(urow + kt * 32 + quad * 8);

    float sl[4] = {0.f, 0.f, 0.f, 0.f};
    #pragma unroll
    for (int nt = 0; nt < 12; ++nt) {
        const int jb = 192 * w + nt * 16;
        #pragma unroll
        for (int rg = 0; rg < 4; ++rg) {
            const float e = __expf(dsc[nt][rg] - mx[rg]);
            sl[rg] += e;
            sm.a.al[quad * 4 + rg][jb + m] = f2bf(e);
        }
    }
    #pragma unroll
    for (int rg = 0; rg < 4; ++rg) {
        float s = sl[rg];
        s += __shfl_xor(s, 1, 64);
        s += __shfl_xor(s, 2, 64);
        s += __shfl_xor(s, 4, 64);
        s += __shfl_xor(s, 8, 64);
        if (m == 0) sm.a.wsum[w][quad * 4 + rg] = s;
    }
    __syncthreads();

    {
        f32x4 acc0 = {0.f, 0.f, 0.f, 0.f};
        f32x4 acc1 = {0.f, 0.f, 0.f, 0.f};
        #pragma unroll
        for (int kt = 0; kt < 24; kt += 2) {
            const int ka = kt * 32, kb = ka + 32;
            bf16x8 a0 = *(const bf16x8*)&sm.a.al[m][ka + quad * 8];
            bf16x8 a1 = *(const bf16x8*)&sm.a.al[m][kb + quad * 8];
            acc0 = __builtin_amdgcn_mfma_f32_16x16x32_bf16(a0, vpre[kt], acc0, 0, 0, 0);
            acc1 = __builtin_amdgcn_mfma_f32_16x16x32_bf16(a1, vpre[kt + 1], acc1, 0, 0, 0);
        }
        #pragma unroll
        for (int rg = 0; rg < 4; ++rg) {
            const int i = quad * 4 + rg;
            const float ri = 1.f / (sm.a.wsum[0][i] + sm.a.wsum[1][i] +
                                    sm.a.wsum[2][i] + sm.a.wsum[3][i]);
            const int row = ((i0 + i) * 8 + l2) * 64 + c;
            h_out[row] = hpre[rg] + ri * (acc0[rg] + acc1[rg]);
        }
    }

    {
        f32x4 acc = {0.f, 0.f, 0.f, 0.f};
        #pragma unroll
        for (int kt = 0; kt < 6; ++kt) {
            const int k0 = kt * 32;
            bf16x8 a = *(const bf16x8*)&sm.a.al[m][192 * w + k0 + quad * 8];
            acc = __builtin_amdgcn_mfma_f32_16x16x32_bf16(a, upre[kt], acc, 0, 0, 0);
        }
        #pragma unroll
        for (int rg = 0; rg < 4; ++rg)
            sm.a.part3[w][quad * 4 + rg][m] = acc[rg];
    }
    __syncthreads();
    if (t < 192) {
        const int i4 = t / 12, kt = t % 12, k4 = kt / 3, s4 = kt % 3;
        const float ri = 1.f / (sm.a.wsum[0][i4] + sm.a.wsum[1][i4] +
                                sm.a.wsum[2][i4] + sm.a.wsum[3][i4]);
        const int uA = k4 * 4, uB = k4 * 4 + 1 + s4;
        const float sA = (sm.a.part3[0][i4][uA] + sm.a.part3[1][i4][uA] +
                          sm.a.part3[2][i4][uA] + sm.a.part3[3][i4][uA]) * ri;
        const float sB = (sm.a.part3[0][i4][uB] + sm.a.part3[1][i4][uB] +
                          sm.a.part3[2][i4][uB] + sm.a.part3[3][i4][uB]) * ri;
        const int idx = ((i0 + i4) * 8 + l2) * 12 + kt;
        x_out[idx] = cdpre + cdpre * sA - sB;
    }
}

extern "C" void kernel_launch(void* const* d_in, const int* in_sizes, int n_in,
                              void* d_out, int out_size, void* d_ws, size_t ws_size,
                              hipStream_t stream) {
    const float* h     = (const float*)d_in[0];
    const float* coord = (const float*)d_in[1];

    float* h_out = (float*)d_out;
    float* x_out = h_out + NN * LL * HH;     // 393216 floats

    short* q_ws  = (short*)d_ws;             // [L][N][64] bf16
    short* k_ws  = q_ws + NN * LL * HH;      // [L][N][64] bf16
    short* vT_ws = k_ws + NN * LL * HH;      // [L][64][N] bf16
    short* UT_ws = vT_ws + NN * LL * HH;     // [L][16][N] bf16

    // barrier counter (line A) + flag (line B, +256 B) at the workspace
    // tail; workspace is re-poisoned each iteration, so re-zero both lines
    // every launch (memset node is capturable)
    unsigned* bar = (unsigned*)((char*)d_ws + ws_size - 512);
    hipMemsetAsync((void*)bar, 0, 512, stream);

    fused_kernel<<<GRID, 256, 0, stream>>>(
        h, coord,
        (const float*)d_in[2],  (const float*)d_in[3],
        (const float*)d_in[4],  (const float*)d_in[5],
        (const float*)d_in[6],  (const float*)d_in[7],
        (const float*)d_in[8],  (const float*)d_in[9],
        (const float*)d_in[10], (const float*)d_in[11],
        (const float*)d_in[12], (const float*)d_in[13],
        (const float*)d_in[14], (const float*)d_in[15],
        (const float*)d_in[16],
        q_ws, k_ws, vT_ws, UT_ws, h_out, x_out, bar);
}

// Round 5
// 115.432 us; speedup vs baseline: 2.3830x; 1.1082x over previous
//
#include <hip/hip_runtime.h>
#include <hip/hip_bf16.h>

#define NN 768
#define LL 8
#define HH 64
#define IT 16     // attn i-tile
#define ABP 776   // bf16 alpha row stride (shorts); 1552 B, 16B-aligned
#define XST 80    // qkv LDS X-tile row stride in shorts (160 B, 16B-aligned)
#define WST 72    // staged-W LDS row stride in shorts (144 B = 9*16, 16B-aligned)

typedef __attribute__((ext_vector_type(8))) short bf16x8;
typedef __attribute__((ext_vector_type(4))) float f32x4;

__device__ __forceinline__ short f2bf(float x) {
    union { __hip_bfloat16 h; short s; } u;
    u.h = __float2bfloat16(x);
    return u.s;
}

__device__ __forceinline__ bf16x8 pack8(float4 lo, float4 hi) {
    bf16x8 r;
    r[0] = f2bf(lo.x); r[1] = f2bf(lo.y); r[2] = f2bf(lo.z); r[3] = f2bf(lo.w);
    r[4] = f2bf(hi.x); r[5] = f2bf(hi.y); r[6] = f2bf(hi.z); r[7] = f2bf(hi.w);
    return r;
}

// Block-cooperative W (fp32, k-major [64][64]) -> bf16 W^T tile in LDS.
__device__ __forceinline__ void stage_W(short (*Wt)[WST],
                                        const float* __restrict__ W, int t) {
    const int n  = t & 63;
    const int kb = (t >> 6) * 16;
    #pragma unroll
    for (int jj = 0; jj < 16; ++jj)
        Wt[n][kb + jj] = f2bf(W[(kb + jj) * 64 + n]);
}

__device__ __forceinline__ void layer_mfma_lds(bf16x8 a0, bf16x8 a1,
                                               const short (*Wt)[WST],
                                               const float* __restrict__ bias,
                                               int m, int quad, bool do_relu,
                                               f32x4 dout[4])
{
    #pragma unroll
    for (int nt = 0; nt < 4; ++nt) {
        const int n = nt * 16 + m;
        bf16x8 b0 = *(const bf16x8*)&Wt[n][quad * 8];
        bf16x8 b1 = *(const bf16x8*)&Wt[n][32 + quad * 8];
        f32x4 d = {0.f, 0.f, 0.f, 0.f};
        d = __builtin_amdgcn_mfma_f32_16x16x32_bf16(a0, b0, d, 0, 0, 0);
        d = __builtin_amdgcn_mfma_f32_16x16x32_bf16(a1, b1, d, 0, 0, 0);
        if (bias) {
            const float bb = bias[n];
            #pragma unroll
            for (int rg = 0; rg < 4; ++rg) d[rg] += bb;
        }
        if (do_relu) {
            #pragma unroll
            for (int rg = 0; rg < 4; ++rg) d[rg] = fmaxf(d[rg], 0.f);
        }
        dout[nt] = d;
    }
}

__device__ __forceinline__ void d_to_X(const f32x4 d[4], short (*X)[XST],
                                       int m, int quad) {
    #pragma unroll
    for (int nt = 0; nt < 4; ++nt)
        #pragma unroll
        for (int rg = 0; rg < 4; ++rg)
            X[quad * 4 + rg][nt * 16 + m] = f2bf(d[nt][rg]);
}

// Kernel 1 v11: k + v + coord_mlp only (q moved into the attn kernel, where
// its sole consumer lives). 192 blocks on 256 CUs -> every CU runs at most
// one block; makespan = one v-chain critical path (round-1's 288 blocks made
// 32 CUs serialize two blocks). Heavy v+cmv chain dispatches first (bb<96).
__global__ __launch_bounds__(256) void kv_kernel(
    const float* __restrict__ h, const float* __restrict__ coord,
    const float* __restrict__ wk1, const float* __restrict__ bk1,
    const float* __restrict__ wk2, const float* __restrict__ bk2,
    const float* __restrict__ wv1, const float* __restrict__ bv1,
    const float* __restrict__ wv2, const float* __restrict__ bv2,
    const float* __restrict__ wc1, const float* __restrict__ bc1,
    const float* __restrict__ wc2,
    short* __restrict__ k_ws, short* __restrict__ vT_ws,
    short* __restrict__ UT_ws)
{
    const int t    = threadIdx.x;
    const int lane = t & 63;
    const int w    = t >> 6;

    const int bb    = blockIdx.x;
    const int chain = (bb < 96) ? 2 : 1;     // 2 = v+cmv (heavy, first), 1 = k
    const int tb    = (bb < 96) ? bb : bb - 96;
    const int rt    = tb * 4 + w;            // 16-row tile, 0..383
    const int r0    = rt * 16;

    const int m    = lane & 15;
    const int quad = lane >> 4;

    __shared__ alignas(16) short Wt[3][64][WST];
    __shared__ alignas(16) short Xs[4][16][XST];
    __shared__ float cms[4][16][4];
    short (*X)[XST] = Xs[w];

    // layer-1 A-frags straight from global h (fp32 -> bf16)
    bf16x8 a0, a1;
    {
        const float* hrow = h + (size_t)(r0 + m) * 64;
        a0 = pack8(*(const float4*)(hrow + quad * 8),
                   *(const float4*)(hrow + quad * 8 + 4));
        a1 = pack8(*(const float4*)(hrow + 32 + quad * 8),
                   *(const float4*)(hrow + 32 + quad * 8 + 4));
    }

    // chain-2 U-build coord operands, prefetched early
    float cpre[3];
    const int rowu = lane >> 2, kk = lane & 3;
    const int gu = r0 + rowu;
    if (chain == 2) {
        #pragma unroll
        for (int s = 0; s < 3; ++s)
            cpre[s] = coord[gu * 12 + kk * 3 + s];
    }

    // block-cooperative weight staging (4 waves share one chain)
    if (chain == 1) { stage_W(Wt[0], wk1, t); stage_W(Wt[1], wk2, t); }
    else            { stage_W(Wt[0], wv1, t); stage_W(Wt[1], wv2, t);
                      stage_W(Wt[2], wc1, t); }
    __syncthreads();

    f32x4 d[4];

    if (chain == 1) {
        layer_mfma_lds(a0, a1, Wt[0], bk1, m, quad, true, d);
        d_to_X(d, X, m, quad);
        __builtin_amdgcn_wave_barrier();
        a0 = *(const bf16x8*)&X[m][quad * 8];
        a1 = *(const bf16x8*)&X[m][32 + quad * 8];
        layer_mfma_lds(a0, a1, Wt[1], bk2, m, quad, true, d);
        #pragma unroll
        for (int nt = 0; nt < 4; ++nt)
            #pragma unroll
            for (int rg = 0; rg < 4; ++rg) {
                const int g = r0 + quad * 4 + rg, i = g >> 3, l = g & 7;
                k_ws[(l * NN + i) * 64 + nt * 16 + m] = f2bf(d[nt][rg]);
            }
    } else {
        layer_mfma_lds(a0, a1, Wt[0], bv1, m, quad, true, d);
        d_to_X(d, X, m, quad);
        __builtin_amdgcn_wave_barrier();
        a0 = *(const bf16x8*)&X[m][quad * 8];
        a1 = *(const bf16x8*)&X[m][32 + quad * 8];
        layer_mfma_lds(a0, a1, Wt[1], bv2, m, quad, true, d);
        // v: transposed stores + back into X (input to coord_mlp)
        #pragma unroll
        for (int nt = 0; nt < 4; ++nt)
            #pragma unroll
            for (int rg = 0; rg < 4; ++rg) {
                const int g = r0 + quad * 4 + rg, i = g >> 3, l = g & 7;
                vT_ws[((size_t)l * 64 + nt * 16 + m) * NN + i] = f2bf(d[nt][rg]);
            }
        d_to_X(d, X, m, quad);
        __builtin_amdgcn_wave_barrier();
        a0 = *(const bf16x8*)&X[m][quad * 8];
        a1 = *(const bf16x8*)&X[m][32 + quad * 8];
        layer_mfma_lds(a0, a1, Wt[2], bc1, m, quad, true, d);
        d_to_X(d, X, m, quad);
        __builtin_amdgcn_wave_barrier();
        a0 = *(const bf16x8*)&X[m][quad * 8];
        a1 = *(const bf16x8*)&X[m][32 + quad * 8];
        // cmv = t1 @ wc2 (no bias/relu); wc2 is [64][4], cols m>=4 zero
        {
            bf16x8 b0, b1;
            #pragma unroll
            for (int j = 0; j < 8; ++j) {
                b0[j] = (m < 4) ? f2bf(wc2[(quad * 8 + j) * 4 + m]) : (short)0;
                b1[j] = (m < 4) ? f2bf(wc2[(32 + quad * 8 + j) * 4 + m]) : (short)0;
            }
            f32x4 dc = {0.f, 0.f, 0.f, 0.f};
            dc = __builtin_amdgcn_mfma_f32_16x16x32_bf16(a0, b0, dc, 0, 0, 0);
            dc = __builtin_amdgcn_mfma_f32_16x16x32_bf16(a1, b1, dc, 0, 0, 0);
            if (m < 4) {
                #pragma unroll
                for (int rg = 0; rg < 4; ++rg)
                    cms[w][quad * 4 + rg][m] = dc[rg];
            }
        }
        __builtin_amdgcn_wave_barrier();
        // U build: lane -> (row = lane>>2, kk = lane&3), 4 seg outputs
        {
            const float cv = cms[w][rowu][kk];
            const int i = gu >> 3, l = gu & 7;
            UT_ws[((size_t)l * 16 + kk * 4 + 0) * NN + i] = f2bf(cv);
            #pragma unroll
            for (int seg = 1; seg < 4; ++seg) {
                const float uval = cv * cpre[seg - 1];
                UT_ws[((size_t)l * 16 + kk * 4 + seg) * NN + i] = f2bf(uval);
            }
        }
    }
}

// Kernel 2 v9: attn with q-MLP fused in. Each block is the sole consumer of
// its 16-row q tile, so q never touches the workspace and needs no
// inter-block sync. All 4 waves compute the q tile redundantly (identical
// values; X1/X2 split avoids the layer1/layer2 overwrite race; no extra
// __syncthreads). LDS is a union with the attn-phase buffers -- aq reads
// finish before each wave's arrival at the wmax __syncthreads, and al writes
// only start after it, so the overlay is race-free.
union SMemA {
    struct {
        short Wt[2][64][WST];   // 18432 B
        short X1[16][XST];      //  2560 B
        short X2[16][XST];      //  2560 B
    } qp;
    struct {
        short al[IT][ABP];      // 24832 B
        float wmax[4][IT];
        float wsum[4][IT];
        float part3[4][IT][16];
    } a;
};

__global__ __launch_bounds__(256, 2) void attn_kernel(
    const short* __restrict__ k_ws, const short* __restrict__ vT_ws,
    const short* __restrict__ UT_ws,
    const float* __restrict__ h, const float* __restrict__ coord,
    const float* __restrict__ wq1, const float* __restrict__ bq1,
    const float* __restrict__ wq2, const float* __restrict__ bq2,
    float* __restrict__ h_out, float* __restrict__ x_out)
{
    const int l    = blockIdx.x & 7;
    const int i0   = (blockIdx.x >> 3) * IT;
    const int t    = threadIdx.x;
    const int lane = t & 63;
    const int w    = t >> 6;
    const int m    = lane & 15;
    const int quad = lane >> 4;

    __shared__ SMemA sm;

    // epilogue operands prefetched at the very top
    const int c = 16 * w + m;
    float hpre[4];
    #pragma unroll
    for (int rg = 0; rg < 4; ++rg)
        hpre[rg] = h[((i0 + quad * 4 + rg) * 8 + l) * 64 + c];
    float cdpre = 0.f;
    if (t < 192)
        cdpre = coord[((i0 + t / 12) * 8 + l) * 12 + (t % 12)];

    // ---- q-MLP for this block's 16 rows (i = i0..i0+15 at frame l) ----
    stage_W(sm.qp.Wt[0], wq1, t);
    stage_W(sm.qp.Wt[1], wq2, t);
    __syncthreads();

    bf16x8 aq0, aq1;
    {
        bf16x8 a0, a1;
        const float* hrow = h + ((size_t)(i0 + m) * 8 + l) * 64;
        a0 = pack8(*(const float4*)(hrow + quad * 8),
                   *(const float4*)(hrow + quad * 8 + 4));
        a1 = pack8(*(const float4*)(hrow + 32 + quad * 8),
                   *(const float4*)(hrow + 32 + quad * 8 + 4));
        f32x4 d[4];
        layer_mfma_lds(a0, a1, sm.qp.Wt[0], bq1, m, quad, true, d);
        d_to_X(d, sm.qp.X1, m, quad);
        __builtin_amdgcn_wave_barrier();
        a0 = *(const bf16x8*)&sm.qp.X1[m][quad * 8];
        a1 = *(const bf16x8*)&sm.qp.X1[m][32 + quad * 8];
        layer_mfma_lds(a0, a1, sm.qp.Wt[1], bq2, m, quad, true, d);
        d_to_X(d, sm.qp.X2, m, quad);
        __builtin_amdgcn_wave_barrier();
        aq0 = *(const bf16x8*)&sm.qp.X2[m][quad * 8];
        aq1 = *(const bf16x8*)&sm.qp.X2[m][32 + quad * 8];
    }

    // ---- scores ----
    f32x4 dsc[12];
    {
        const short* kl = k_ws + (size_t)l * NN * 64;
        #pragma unroll
        for (int nt = 0; nt < 12; ++nt) {
            const int jb = 192 * w + nt * 16;
            const short* krow = kl + (size_t)(jb + m) * 64;
            bf16x8 b0 = *(const bf16x8*)(krow + quad * 8);
            bf16x8 b1 = *(const bf16x8*)(krow + 32 + quad * 8);
            f32x4 d = {0.f, 0.f, 0.f, 0.f};
            d = __builtin_amdgcn_mfma_f32_16x16x32_bf16(aq0, b0, d, 0, 0, 0);
            d = __builtin_amdgcn_mfma_f32_16x16x32_bf16(aq1, b1, d, 0, 0, 0);
            dsc[nt] = d;
        }
    }

    float mx[4];
    #pragma unroll
    for (int rg = 0; rg < 4; ++rg) {
        float mm = dsc[0][rg];
        #pragma unroll
        for (int nt = 1; nt < 12; ++nt) mm = fmaxf(mm, dsc[nt][rg]);
        mm = fmaxf(mm, __shfl_xor(mm, 1, 64));
        mm = fmaxf(mm, __shfl_xor(mm, 2, 64));
        mm = fmaxf(mm, __shfl_xor(mm, 4, 64));
        mm = fmaxf(mm, __shfl_xor(mm, 8, 64));
        if (m == 0) sm.a.wmax[w][quad * 4 + rg] = mm;
    }
    __syncthreads();
    #pragma unroll
    for (int rg = 0; rg < 4; ++rg) {
        const int row = quad * 4 + rg;
        mx[rg] = fmaxf(fmaxf(sm.a.wmax[0][row], sm.a.wmax[1][row]),
                       fmaxf(sm.a.wmax[2][row], sm.a.wmax[3][row]));
    }

    // issue ALL vT/UT fragment loads now; they complete under the exp phase
    const short* vrow = vT_ws + ((size_t)l * 64 + 16 * w + m) * NN;
    const short* urow = UT_ws + ((size_t)l * 16 + m) * NN + 192 * w;
    bf16x8 vpre[24];
    bf16x8 upre[6];
    #pragma unroll
    for (int kt = 0; kt < 24; ++kt)
        vpre[kt] = *(const bf16x8*)(vrow + kt * 32 + quad * 8);
    #pragma unroll
    for (int kt = 0; kt < 6; ++kt)
        upre[kt] = *(const bf16x8*)(urow + kt * 32 + quad * 8);

    float sl[4] = {0.f, 0.f, 0.f, 0.f};
    #pragma unroll
    for (int nt = 0; nt < 12; ++nt) {
        const int jb = 192 * w + nt * 16;
        #pragma unroll
        for (int rg = 0; rg < 4; ++rg) {
            const float e = __expf(dsc[nt][rg] - mx[rg]);
            sl[rg] += e;
            sm.a.al[quad * 4 + rg][jb + m] = f2bf(e);
        }
    }
    #pragma unroll
    for (int rg = 0; rg < 4; ++rg) {
        float s = sl[rg];
        s += __shfl_xor(s, 1, 64);
        s += __shfl_xor(s, 2, 64);
        s += __shfl_xor(s, 4, 64);
        s += __shfl_xor(s, 8, 64);
        if (m == 0) sm.a.wsum[w][quad * 4 + rg] = s;
    }
    __syncthreads();

    {
        f32x4 acc0 = {0.f, 0.f, 0.f, 0.f};
        f32x4 acc1 = {0.f, 0.f, 0.f, 0.f};
        #pragma unroll
        for (int kt = 0; kt < 24; kt += 2) {
            const int ka = kt * 32, kb = ka + 32;
            bf16x8 a0 = *(const bf16x8*)&sm.a.al[m][ka + quad * 8];
            bf16x8 a1 = *(const bf16x8*)&sm.a.al[m][kb + quad * 8];
            acc0 = __builtin_amdgcn_mfma_f32_16x16x32_bf16(a0, vpre[kt], acc0, 0, 0, 0);
            acc1 = __builtin_amdgcn_mfma_f32_16x16x32_bf16(a1, vpre[kt + 1], acc1, 0, 0, 0);
        }
        #pragma unroll
        for (int rg = 0; rg < 4; ++rg) {
            const int i = quad * 4 + rg;
            const float ri = 1.f / (sm.a.wsum[0][i] + sm.a.wsum[1][i] +
                                    sm.a.wsum[2][i] + sm.a.wsum[3][i]);
            const int row = ((i0 + i) * 8 + l) * 64 + c;
            h_out[row] = hpre[rg] + ri * (acc0[rg] + acc1[rg]);
        }
    }

    {
        f32x4 acc = {0.f, 0.f, 0.f, 0.f};
        #pragma unroll
        for (int kt = 0; kt < 6; ++kt) {
            const int k0 = kt * 32;
            bf16x8 a = *(const bf16x8*)&sm.a.al[m][192 * w + k0 + quad * 8];
            acc = __builtin_amdgcn_mfma_f32_16x16x32_bf16(a, upre[kt], acc, 0, 0, 0);
        }
        #pragma unroll
        for (int rg = 0; rg < 4; ++rg)
            sm.a.part3[w][quad * 4 + rg][m] = acc[rg];
    }
    __syncthreads();
    if (t < 192) {
        const int i4 = t / 12, kt = t % 12, k4 = kt / 3, s4 = kt % 3;
        const float ri = 1.f / (sm.a.wsum[0][i4] + sm.a.wsum[1][i4] +
                                sm.a.wsum[2][i4] + sm.a.wsum[3][i4]);
        const int uA = k4 * 4, uB = k4 * 4 + 1 + s4;
        const float sA = (sm.a.part3[0][i4][uA] + sm.a.part3[1][i4][uA] +
                          sm.a.part3[2][i4][uA] + sm.a.part3[3][i4][uA]) * ri;
        const float sB = (sm.a.part3[0][i4][uB] + sm.a.part3[1][i4][uB] +
                          sm.a.part3[2][i4][uB] + sm.a.part3[3][i4][uB]) * ri;
        const int idx = ((i0 + i4) * 8 + l) * 12 + kt;
        x_out[idx] = cdpre + cdpre * sA - sB;
    }
}

extern "C" void kernel_launch(void* const* d_in, const int* in_sizes, int n_in,
                              void* d_out, int out_size, void* d_ws, size_t ws_size,
                              hipStream_t stream) {
    const float* h     = (const float*)d_in[0];
    const float* coord = (const float*)d_in[1];

    float* h_out = (float*)d_out;
    float* x_out = h_out + NN * LL * HH;     // 393216 floats

    short* q_ws  = (short*)d_ws;             // unused (q fused into attn)
    short* k_ws  = q_ws + NN * LL * HH;      // [L][N][64] bf16
    short* vT_ws = k_ws + NN * LL * HH;      // [L][64][N] bf16
    short* UT_ws = vT_ws + NN * LL * HH;     // [L][16][N] bf16

    kv_kernel<<<192, 256, 0, stream>>>(
        h, coord,
        (const float*)d_in[6],  (const float*)d_in[7],
        (const float*)d_in[8],  (const float*)d_in[9],
        (const float*)d_in[10], (const float*)d_in[11],
        (const float*)d_in[12], (const float*)d_in[13],
        (const float*)d_in[14], (const float*)d_in[15],
        (const float*)d_in[16],
        k_ws, vT_ws, UT_ws);

    attn_kernel<<<(NN / IT) * LL, 256, 0, stream>>>(
        k_ws, vT_ws, UT_ws, h, coord,
        (const float*)d_in[2], (const float*)d_in[3],
        (const float*)d_in[4], (const float*)d_in[5],
        h_out, x_out);
}

// Round 6
// 109.335 us; speedup vs baseline: 2.5159x; 1.0558x over previous
//
#include <hip/hip_runtime.h>
#include <hip/hip_bf16.h>

#define NN 768
#define LL 8
#define HH 64
#define IT 16     // attn i-tile
#define ABP 776   // bf16 alpha row stride (shorts); 1552 B, 16B-aligned
#define XST 80    // qkv LDS X-tile row stride in shorts (160 B, 16B-aligned)
#define WST 72    // staged-W LDS row stride in shorts (144 B = 9*16, 16B-aligned)

typedef __attribute__((ext_vector_type(8))) short bf16x8;
typedef __attribute__((ext_vector_type(4))) float f32x4;

__device__ __forceinline__ short f2bf(float x) {
    union { __hip_bfloat16 h; short s; } u;
    u.h = __float2bfloat16(x);
    return u.s;
}

__device__ __forceinline__ bf16x8 pack8(float4 lo, float4 hi) {
    bf16x8 r;
    r[0] = f2bf(lo.x); r[1] = f2bf(lo.y); r[2] = f2bf(lo.z); r[3] = f2bf(lo.w);
    r[4] = f2bf(hi.x); r[5] = f2bf(hi.y); r[6] = f2bf(hi.z); r[7] = f2bf(hi.w);
    return r;
}

// Block-cooperative W (fp32, k-major [64][64]) -> bf16 W^T tile in LDS.
__device__ __forceinline__ void stage_W(short (*Wt)[WST],
                                        const float* __restrict__ W, int t) {
    const int n  = t & 63;
    const int kb = (t >> 6) * 16;
    #pragma unroll
    for (int jj = 0; jj < 16; ++jj)
        Wt[n][kb + jj] = f2bf(W[(kb + jj) * 64 + n]);
}

__device__ __forceinline__ void layer_mfma_lds(bf16x8 a0, bf16x8 a1,
                                               const short (*Wt)[WST],
                                               const float* __restrict__ bias,
                                               int m, int quad, bool do_relu,
                                               f32x4 dout[4])
{
    #pragma unroll
    for (int nt = 0; nt < 4; ++nt) {
        const int n = nt * 16 + m;
        bf16x8 b0 = *(const bf16x8*)&Wt[n][quad * 8];
        bf16x8 b1 = *(const bf16x8*)&Wt[n][32 + quad * 8];
        f32x4 d = {0.f, 0.f, 0.f, 0.f};
        d = __builtin_amdgcn_mfma_f32_16x16x32_bf16(a0, b0, d, 0, 0, 0);
        d = __builtin_amdgcn_mfma_f32_16x16x32_bf16(a1, b1, d, 0, 0, 0);
        if (bias) {
            const float bb = bias[n];
            #pragma unroll
            for (int rg = 0; rg < 4; ++rg) d[rg] += bb;
        }
        if (do_relu) {
            #pragma unroll
            for (int rg = 0; rg < 4; ++rg) d[rg] = fmaxf(d[rg], 0.f);
        }
        dout[nt] = d;
    }
}

__device__ __forceinline__ void d_to_X(const f32x4 d[4], short (*X)[XST],
                                       int m, int quad) {
    #pragma unroll
    for (int nt = 0; nt < 4; ++nt)
        #pragma unroll
        for (int rg = 0; rg < 4; ++rg)
            X[quad * 4 + rg][nt * 16 + m] = f2bf(d[nt][rg]);
}

// Kernel 1 v12: 192 balanced blocks on 256 CUs (<= 1 block/CU, no makespan
// tail -- round-1 ran 288 blocks so 32 CUs serialized two).
//   bb  0..95 : v + coord_mlp chain  (4 MFMA layers + vT/UT stores)
//   bb 96..191: merged q+k chain     (2+2 MFMA layers; h frags loaded once)
// Both chain types have the same 4-layer critical path.
__global__ __launch_bounds__(256) void qkv_kernel(
    const float* __restrict__ h, const float* __restrict__ coord,
    const float* __restrict__ wq1, const float* __restrict__ bq1,
    const float* __restrict__ wq2, const float* __restrict__ bq2,
    const float* __restrict__ wk1, const float* __restrict__ bk1,
    const float* __restrict__ wk2, const float* __restrict__ bk2,
    const float* __restrict__ wv1, const float* __restrict__ bv1,
    const float* __restrict__ wv2, const float* __restrict__ bv2,
    const float* __restrict__ wc1, const float* __restrict__ bc1,
    const float* __restrict__ wc2,
    short* __restrict__ q_ws, short* __restrict__ k_ws,
    short* __restrict__ vT_ws, short* __restrict__ UT_ws)
{
    const int t    = threadIdx.x;
    const int lane = t & 63;
    const int w    = t >> 6;

    const int bb    = blockIdx.x;
    const bool vcmv = (bb < 96);             // heavy-ish chain first
    const int tb    = vcmv ? bb : bb - 96;
    const int rt    = tb * 4 + w;            // 16-row tile, 0..383
    const int r0    = rt * 16;

    const int m    = lane & 15;
    const int quad = lane >> 4;

    __shared__ alignas(16) short Wt[4][64][WST];
    __shared__ alignas(16) short Xs[4][16][XST];
    __shared__ float cms[4][16][4];
    short (*X)[XST] = Xs[w];

    // layer-1 A-frags straight from global h (fp32 -> bf16); kept in
    // registers and reused by BOTH the q and k layer-1 MFMAs.
    bf16x8 ha0, ha1;
    {
        const float* hrow = h + (size_t)(r0 + m) * 64;
        ha0 = pack8(*(const float4*)(hrow + quad * 8),
                    *(const float4*)(hrow + quad * 8 + 4));
        ha1 = pack8(*(const float4*)(hrow + 32 + quad * 8),
                    *(const float4*)(hrow + 32 + quad * 8 + 4));
    }

    // v-chain U-build coord operands, prefetched early
    float cpre[3];
    const int rowu = lane >> 2, kk = lane & 3;
    const int gu = r0 + rowu;
    if (vcmv) {
        #pragma unroll
        for (int s = 0; s < 3; ++s)
            cpre[s] = coord[gu * 12 + kk * 3 + s];
    }

    // block-cooperative weight staging (4 waves share one chain)
    if (vcmv) { stage_W(Wt[0], wv1, t); stage_W(Wt[1], wv2, t);
                stage_W(Wt[2], wc1, t); }
    else      { stage_W(Wt[0], wq1, t); stage_W(Wt[1], wq2, t);
                stage_W(Wt[2], wk1, t); stage_W(Wt[3], wk2, t); }
    __syncthreads();

    f32x4 d[4];
    bf16x8 a0, a1;

    if (!vcmv) {
        // ---- q ----
        layer_mfma_lds(ha0, ha1, Wt[0], bq1, m, quad, true, d);
        d_to_X(d, X, m, quad);
        __builtin_amdgcn_wave_barrier();
        a0 = *(const bf16x8*)&X[m][quad * 8];
        a1 = *(const bf16x8*)&X[m][32 + quad * 8];
        layer_mfma_lds(a0, a1, Wt[1], bq2, m, quad, true, d);
        #pragma unroll
        for (int nt = 0; nt < 4; ++nt)
            #pragma unroll
            for (int rg = 0; rg < 4; ++rg) {
                const int g = r0 + quad * 4 + rg, i = g >> 3, l = g & 7;
                q_ws[(l * NN + i) * 64 + nt * 16 + m] = f2bf(d[nt][rg]);
            }
        __builtin_amdgcn_wave_barrier();
        // ---- k (reuses ha0/ha1) ----
        layer_mfma_lds(ha0, ha1, Wt[2], bk1, m, quad, true, d);
        d_to_X(d, X, m, quad);
        __builtin_amdgcn_wave_barrier();
        a0 = *(const bf16x8*)&X[m][quad * 8];
        a1 = *(const bf16x8*)&X[m][32 + quad * 8];
        layer_mfma_lds(a0, a1, Wt[3], bk2, m, quad, true, d);
        #pragma unroll
        for (int nt = 0; nt < 4; ++nt)
            #pragma unroll
            for (int rg = 0; rg < 4; ++rg) {
                const int g = r0 + quad * 4 + rg, i = g >> 3, l = g & 7;
                k_ws[(l * NN + i) * 64 + nt * 16 + m] = f2bf(d[nt][rg]);
            }
    } else {
        // ---- v + coord_mlp ----
        layer_mfma_lds(ha0, ha1, Wt[0], bv1, m, quad, true, d);
        d_to_X(d, X, m, quad);
        __builtin_amdgcn_wave_barrier();
        a0 = *(const bf16x8*)&X[m][quad * 8];
        a1 = *(const bf16x8*)&X[m][32 + quad * 8];
        layer_mfma_lds(a0, a1, Wt[1], bv2, m, quad, true, d);
        // v: transposed stores + back into X (input to coord_mlp)
        #pragma unroll
        for (int nt = 0; nt < 4; ++nt)
            #pragma unroll
            for (int rg = 0; rg < 4; ++rg) {
                const int g = r0 + quad * 4 + rg, i = g >> 3, l = g & 7;
                vT_ws[((size_t)l * 64 + nt * 16 + m) * NN + i] = f2bf(d[nt][rg]);
            }
        d_to_X(d, X, m, quad);
        __builtin_amdgcn_wave_barrier();
        a0 = *(const bf16x8*)&X[m][quad * 8];
        a1 = *(const bf16x8*)&X[m][32 + quad * 8];
        layer_mfma_lds(a0, a1, Wt[2], bc1, m, quad, true, d);
        d_to_X(d, X, m, quad);
        __builtin_amdgcn_wave_barrier();
        a0 = *(const bf16x8*)&X[m][quad * 8];
        a1 = *(const bf16x8*)&X[m][32 + quad * 8];
        // cmv = t1 @ wc2 (no bias/relu); wc2 is [64][4], cols m>=4 zero
        {
            bf16x8 b0, b1;
            #pragma unroll
            for (int j = 0; j < 8; ++j) {
                b0[j] = (m < 4) ? f2bf(wc2[(quad * 8 + j) * 4 + m]) : (short)0;
                b1[j] = (m < 4) ? f2bf(wc2[(32 + quad * 8 + j) * 4 + m]) : (short)0;
            }
            f32x4 dc = {0.f, 0.f, 0.f, 0.f};
            dc = __builtin_amdgcn_mfma_f32_16x16x32_bf16(a0, b0, dc, 0, 0, 0);
            dc = __builtin_amdgcn_mfma_f32_16x16x32_bf16(a1, b1, dc, 0, 0, 0);
            if (m < 4) {
                #pragma unroll
                for (int rg = 0; rg < 4; ++rg)
                    cms[w][quad * 4 + rg][m] = dc[rg];
            }
        }
        __builtin_amdgcn_wave_barrier();
        // U build: lane -> (row = lane>>2, kk = lane&3), 4 seg outputs
        {
            const float cv = cms[w][rowu][kk];
            const int i = gu >> 3, l = gu & 7;
            UT_ws[((size_t)l * 16 + kk * 4 + 0) * NN + i] = f2bf(cv);
            #pragma unroll
            for (int seg = 1; seg < 4; ++seg) {
                const float uval = cv * cpre[seg - 1];
                UT_ws[((size_t)l * 16 + kk * 4 + seg) * NN + i] = f2bf(uval);
            }
        }
    }
}

// Kernel 2 = round-1's attn kernel verbatim (benched 110.2 us in that
// config): register-resident scores; vT/UT fragments prefetched into
// registers during the softmax phase; h/coord epilogue operands prefetched
// at the top; smS folded into the 192-thread epilogue.
__global__ __launch_bounds__(256, 2) void attn_kernel(
    const short* __restrict__ q_ws, const short* __restrict__ k_ws,
    const short* __restrict__ vT_ws, const short* __restrict__ UT_ws,
    const float* __restrict__ h, const float* __restrict__ coord,
    float* __restrict__ h_out, float* __restrict__ x_out)
{
    const int l    = blockIdx.x & 7;
    const int i0   = (blockIdx.x >> 3) * IT;
    const int t    = threadIdx.x;
    const int lane = t & 63;
    const int w    = t >> 6;
    const int m    = lane & 15;
    const int quad = lane >> 4;

    __shared__ alignas(16) short al[IT][ABP];
    __shared__ float wmax[4][IT];
    __shared__ float wsum[4][IT];
    __shared__ float part3[4][IT][16];

    const int c = 16 * w + m;
    float hpre[4];
    #pragma unroll
    for (int rg = 0; rg < 4; ++rg)
        hpre[rg] = h[((i0 + quad * 4 + rg) * 8 + l) * 64 + c];
    float cdpre = 0.f;
    if (t < 192)
        cdpre = coord[((i0 + t / 12) * 8 + l) * 12 + (t % 12)];

    const bf16x8 aq0 = *(const bf16x8*)&q_ws[((size_t)l * NN + i0 + m) * 64 + quad * 8];
    const bf16x8 aq1 = *(const bf16x8*)&q_ws[((size_t)l * NN + i0 + m) * 64 + 32 + quad * 8];

    f32x4 dsc[12];
    {
        const short* kl = k_ws + (size_t)l * NN * 64;
        #pragma unroll
        for (int nt = 0; nt < 12; ++nt) {
            const int jb = 192 * w + nt * 16;
            const short* krow = kl + (size_t)(jb + m) * 64;
            bf16x8 b0 = *(const bf16x8*)(krow + quad * 8);
            bf16x8 b1 = *(const bf16x8*)(krow + 32 + quad * 8);
            f32x4 d = {0.f, 0.f, 0.f, 0.f};
            d = __builtin_amdgcn_mfma_f32_16x16x32_bf16(aq0, b0, d, 0, 0, 0);
            d = __builtin_amdgcn_mfma_f32_16x16x32_bf16(aq1, b1, d, 0, 0, 0);
            dsc[nt] = d;
        }
    }

    float mx[4];
    #pragma unroll
    for (int rg = 0; rg < 4; ++rg) {
        float mm = dsc[0][rg];
        #pragma unroll
        for (int nt = 1; nt < 12; ++nt) mm = fmaxf(mm, dsc[nt][rg]);
        mm = fmaxf(mm, __shfl_xor(mm, 1, 64));
        mm = fmaxf(mm, __shfl_xor(mm, 2, 64));
        mm = fmaxf(mm, __shfl_xor(mm, 4, 64));
        mm = fmaxf(mm, __shfl_xor(mm, 8, 64));
        if (m == 0) wmax[w][quad * 4 + rg] = mm;
    }
    __syncthreads();
    #pragma unroll
    for (int rg = 0; rg < 4; ++rg) {
        const int row = quad * 4 + rg;
        mx[rg] = fmaxf(fmaxf(wmax[0][row], wmax[1][row]),
                       fmaxf(wmax[2][row], wmax[3][row]));
    }

    // issue ALL vT/UT fragment loads now; they complete under the exp phase
    const short* vrow = vT_ws + ((size_t)l * 64 + 16 * w + m) * NN;
    const short* urow = UT_ws + ((size_t)l * 16 + m) * NN + 192 * w;
    bf16x8 vpre[24];
    bf16x8 upre[6];
    #pragma unroll
    for (int kt = 0; kt < 24; ++kt)
        vpre[kt] = *(const bf16x8*)(vrow + kt * 32 + quad * 8);
    #pragma unroll
    for (int kt = 0; kt < 6; ++kt)
        upre[kt] = *(const bf16x8*)(urow + kt * 32 + quad * 8);

    float sl[4] = {0.f, 0.f, 0.f, 0.f};
    #pragma unroll
    for (int nt = 0; nt < 12; ++nt) {
        const int jb = 192 * w + nt * 16;
        #pragma unroll
        for (int rg = 0; rg < 4; ++rg) {
            const float e = __expf(dsc[nt][rg] - mx[rg]);
            sl[rg] += e;
            al[quad * 4 + rg][jb + m] = f2bf(e);
        }
    }
    #pragma unroll
    for (int rg = 0; rg < 4; ++rg) {
        float s = sl[rg];
        s += __shfl_xor(s, 1, 64);
        s += __shfl_xor(s, 2, 64);
        s += __shfl_xor(s, 4, 64);
        s += __shfl_xor(s, 8, 64);
        if (m == 0) wsum[w][quad * 4 + rg] = s;
    }
    __syncthreads();

    {
        f32x4 acc0 = {0.f, 0.f, 0.f, 0.f};
        f32x4 acc1 = {0.f, 0.f, 0.f, 0.f};
        #pragma unroll
        for (int kt = 0; kt < 24; kt += 2) {
            const int ka = kt * 32, kb = ka + 32;
            bf16x8 a0 = *(const bf16x8*)&al[m][ka + quad * 8];
            bf16x8 a1 = *(const bf16x8*)&al[m][kb + quad * 8];
            acc0 = __builtin_amdgcn_mfma_f32_16x16x32_bf16(a0, vpre[kt], acc0, 0, 0, 0);
            acc1 = __builtin_amdgcn_mfma_f32_16x16x32_bf16(a1, vpre[kt + 1], acc1, 0, 0, 0);
        }
        #pragma unroll
        for (int rg = 0; rg < 4; ++rg) {
            const int i = quad * 4 + rg;
            const float ri = 1.f / (wsum[0][i] + wsum[1][i] +
                                    wsum[2][i] + wsum[3][i]);
            const int row = ((i0 + i) * 8 + l) * 64 + c;
            h_out[row] = hpre[rg] + ri * (acc0[rg] + acc1[rg]);
        }
    }

    {
        f32x4 acc = {0.f, 0.f, 0.f, 0.f};
        #pragma unroll
        for (int kt = 0; kt < 6; ++kt) {
            const int k0 = kt * 32;
            bf16x8 a = *(const bf16x8*)&al[m][192 * w + k0 + quad * 8];
            acc = __builtin_amdgcn_mfma_f32_16x16x32_bf16(a, upre[kt], acc, 0, 0, 0);
        }
        #pragma unroll
        for (int rg = 0; rg < 4; ++rg)
            part3[w][quad * 4 + rg][m] = acc[rg];
    }
    __syncthreads();
    if (t < 192) {
        const int i4 = t / 12, kt = t % 12, k4 = kt / 3, s4 = kt % 3;
        const float ri = 1.f / (wsum[0][i4] + wsum[1][i4] +
                                wsum[2][i4] + wsum[3][i4]);
        const int uA = k4 * 4, uB = k4 * 4 + 1 + s4;
        const float sA = (part3[0][i4][uA] + part3[1][i4][uA] +
                          part3[2][i4][uA] + part3[3][i4][uA]) * ri;
        const float sB = (part3[0][i4][uB] + part3[1][i4][uB] +
                          part3[2][i4][uB] + part3[3][i4][uB]) * ri;
        const int idx = ((i0 + i4) * 8 + l) * 12 + kt;
        x_out[idx] = cdpre + cdpre * sA - sB;
    }
}

extern "C" void kernel_launch(void* const* d_in, const int* in_sizes, int n_in,
                              void* d_out, int out_size, void* d_ws, size_t ws_size,
                              hipStream_t stream) {
    const float* h     = (const float*)d_in[0];
    const float* coord = (const float*)d_in[1];

    float* h_out = (float*)d_out;
    float* x_out = h_out + NN * LL * HH;     // 393216 floats

    short* q_ws  = (short*)d_ws;             // [L][N][64] bf16
    short* k_ws  = q_ws + NN * LL * HH;      // [L][N][64] bf16
    short* vT_ws = k_ws + NN * LL * HH;      // [L][64][N] bf16
    short* UT_ws = vT_ws + NN * LL * HH;     // [L][16][N] bf16

    qkv_kernel<<<192, 256, 0, stream>>>(
        h, coord,
        (const float*)d_in[2],  (const float*)d_in[3],
        (const float*)d_in[4],  (const float*)d_in[5],
        (const float*)d_in[6],  (const float*)d_in[7],
        (const float*)d_in[8],  (const float*)d_in[9],
        (const float*)d_in[10], (const float*)d_in[11],
        (const float*)d_in[12], (const float*)d_in[13],
        (const float*)d_in[14], (const float*)d_in[15],
        (const float*)d_in[16],
        q_ws, k_ws, vT_ws, UT_ws);

    attn_kernel<<<(NN / IT) * LL, 256, 0, stream>>>(
        q_ws, k_ws, vT_ws, UT_ws, h, coord, h_out, x_out);
}